// Round 1
// baseline (6968.465 us; speedup 1.0000x reference)
//
#include <hip/hip_runtime.h>

#define NPTS 8192
#define NB 2

__device__ __forceinline__ float lrelu(float x) { return x > 0.f ? x : 0.2f * x; }
__device__ __forceinline__ float4 lrelu4(float4 a) {
    return make_float4(lrelu(a.x), lrelu(a.y), lrelu(a.z), lrelu(a.w));
}
__device__ __forceinline__ float4 fmax4(float4 a, float4 b) {
    return make_float4(fmaxf(a.x, b.x), fmaxf(a.y, b.y), fmaxf(a.z, b.z), fmaxf(a.w, b.w));
}

// ---------------- conv_in: feature [B,128,N] -> x0 [B*N,32], leaky ----------------
__global__ void k_conv_in(const float* __restrict__ f, const float* __restrict__ W,
                          const float* __restrict__ bias, float* __restrict__ out) {
    int gid = blockIdx.x * blockDim.x + threadIdx.x;   // over B*N
    int b = gid >> 13, n = gid & (NPTS - 1);
    const float* fb = f + ((size_t)b << 20) + n;       // b*128*8192
    float acc[32];
    #pragma unroll
    for (int o = 0; o < 32; ++o) acc[o] = bias[o];
    #pragma unroll 4
    for (int c = 0; c < 128; ++c) {
        float xc = fb[(size_t)c * NPTS];               // coalesced across lanes
        #pragma unroll
        for (int o = 0; o < 32; ++o) acc[o] += xc * W[o * 128 + c];  // uniform -> s_load
    }
    float4* op = (float4*)(out + (size_t)gid * 32);
    #pragma unroll
    for (int o4 = 0; o4 < 8; ++o4)
        op[o4] = make_float4(lrelu(acc[o4 * 4]), lrelu(acc[o4 * 4 + 1]),
                             lrelu(acc[o4 * 4 + 2]), lrelu(acc[o4 * 4 + 3]));
}

// ---------------- kNN: x [B*N,32] -> idx [B,N,K] ----------------
// block: 256 threads = 8 j-segments (interleaved mod 8) x 32; each thread owns 2 points.
// 64 points per block, grid = B*N/64 = 256 blocks.
template <int K>
__global__ __launch_bounds__(256) void k_knn(const float* __restrict__ x, int* __restrict__ idx_out) {
    __shared__ __align__(16) float Xt[128 * 32];
    __shared__ float sqt[128];
    __shared__ float cd[64 * 8 * K];
    __shared__ int ci[64 * 8 * K];

    int tid = threadIdx.x;
    int s = tid >> 5, q = tid & 31;
    int b = blockIdx.x >> 7;                // / (8192/64)
    int pbase = (blockIdx.x & 127) << 6;    // *64
    const float* xb = x + ((size_t)b * NPTS) * 32;

    int p0 = pbase + q, p1 = pbase + q + 32;
    float4 xi0v[8], xi1v[8];
    {
        const float4* r0 = (const float4*)(xb + (size_t)p0 * 32);
        const float4* r1 = (const float4*)(xb + (size_t)p1 * 32);
        #pragma unroll
        for (int u = 0; u < 8; ++u) { xi0v[u] = r0[u]; xi1v[u] = r1[u]; }
    }
    float bd0[K], bd1[K];
    int bi0[K], bi1[K];
    #pragma unroll
    for (int r = 0; r < K; ++r) { bd0[r] = 1e30f; bd1[r] = 1e30f; bi0[r] = 0; bi1[r] = 0; }

    for (int t = 0; t < NPTS / 128; ++t) {
        __syncthreads();
        const float4* src = (const float4*)(xb + (size_t)t * 128 * 32);
        float4* dst = (float4*)Xt;
        float ssq = 0.f;
        #pragma unroll
        for (int u = 0; u < 4; ++u) {
            float4 v = src[tid * 4 + u];
            dst[tid * 4 + u] = v;
            ssq += v.x * v.x + v.y * v.y + v.z * v.z + v.w * v.w;
        }
        float so = __shfl_xor(ssq, 1);
        if ((tid & 1) == 0) sqt[tid >> 1] = ssq + so;
        __syncthreads();
        #pragma unroll 2
        for (int m = 0; m < 16; ++m) {
            int jj = s + (m << 3);
            const float4* xr = (const float4*)(Xt + jj * 32);
            float dot0 = 0.f, dot1 = 0.f;
            #pragma unroll
            for (int c = 0; c < 8; ++c) {
                float4 xv = xr[c];
                float4 a = xi0v[c];
                float4 e = xi1v[c];
                dot0 += xv.x * a.x + xv.y * a.y + xv.z * a.z + xv.w * a.w;
                dot1 += xv.x * e.x + xv.y * e.y + xv.z * e.z + xv.w * e.w;
            }
            float sj = sqt[jj];
            float d0 = sj - 2.f * dot0;   // rank key: sq_j - 2<xi,xj> (sq_i const offset)
            float d1 = sj - 2.f * dot1;
            int j = (t << 7) + jj;
            if (d0 < bd0[K - 1]) {        // sorted-ascending insertion, all static indices
                float dd = d0; int ji = j;
                #pragma unroll
                for (int r = 0; r < K; ++r) {
                    if (dd < bd0[r]) {
                        float tf = bd0[r]; bd0[r] = dd; dd = tf;
                        int ti = bi0[r]; bi0[r] = ji; ji = ti;
                    }
                }
            }
            if (d1 < bd1[K - 1]) {
                float dd = d1; int ji = j;
                #pragma unroll
                for (int r = 0; r < K; ++r) {
                    if (dd < bd1[r]) {
                        float tf = bd1[r]; bd1[r] = dd; dd = tf;
                        int ti = bi1[r]; bi1[r] = ji; ji = ti;
                    }
                }
            }
        }
    }
    __syncthreads();
    #pragma unroll
    for (int r = 0; r < K; ++r) {
        cd[(q * 8 + s) * K + r] = bd0[r];
        ci[(q * 8 + s) * K + r] = bi0[r];
        cd[((q + 32) * 8 + s) * K + r] = bd1[r];
        ci[((q + 32) * 8 + s) * K + r] = bi1[r];
    }
    __syncthreads();
    if (tid < 64) {   // merge 8 segment lists per point, (dist, idx) lexicographic
        float* md = cd + tid * 8 * K;
        int* mi = ci + tid * 8 * K;
        int* op = idx_out + ((size_t)b * NPTS + pbase + tid) * K;
        for (int r = 0; r < K; ++r) {
            float best = 1e30f; int bj = 0x7fffffff; int bs = 0;
            for (int u = 0; u < 8 * K; ++u) {
                float dv = md[u]; int jv = mi[u];
                if (dv < best || (dv == best && jv < bj)) { best = dv; bj = jv; bs = u; }
            }
            md[bs] = 1e30f;
            op[r] = bj;
        }
    }
}

// ---------------- EdgeConv: x [B*N,32] + idx -> y [B*N,128] ----------------
// 4-output x 4-edge register tiles; both MLP layers stream float4 from LDS.
template <int K>
__global__ void k_edgeconv(const float* __restrict__ x, const int* __restrict__ idx,
                           const float* __restrict__ Wa, const float* __restrict__ ba,
                           const float* __restrict__ Wb, const float* __restrict__ bb,
                           float* __restrict__ y) {
    constexpr int EG = (K == 12) ? 6 : 8;   // edge-groups of 4
    constexpr int NT = 32 * EG;             // 192 or 256 threads
    constexpr int PI = (4 * EG) / K;        // points per iteration: 2 or 8
    constexpr int EPI = PI * K;             // edges per iteration: 24 or 32
    constexpr int PPB = 64;                 // points per block

    __shared__ __align__(16) float WaT[64 * 128];
    __shared__ __align__(16) float WbT[128 * 128];
    __shared__ __align__(16) float ba_s[128];
    __shared__ __align__(16) float bb_s[128];
    __shared__ __align__(16) float E[32 * 72];
    __shared__ __align__(16) float H1[32 * 132];
    __shared__ __align__(16) float P[(K == 12) ? 6 * 128 : 4];

    int tid = threadIdx.x;
    for (int i = tid; i < 64 * 128; i += NT) WaT[i] = Wa[(i & 127) * 64 + (i >> 7)];
    for (int i = tid; i < 128 * 128; i += NT) WbT[i] = Wb[(i & 127) * 128 + (i >> 7)];
    for (int i = tid; i < 128; i += NT) { ba_s[i] = ba[i]; bb_s[i] = bb[i]; }

    int b = blockIdx.x >> 7;
    int pbase = (blockIdx.x & 127) * PPB;
    const float* xb = x + ((size_t)b * NPTS) * 32;
    const int* idxb = idx + ((size_t)b * NPTS) * K;
    float* yb = y + ((size_t)b * NPTS) * 128;

    int og = tid & 31, eg = tid >> 5;

    for (int it = 0; it < PPB / PI; ++it) {
        int pt0 = pbase + it * PI;
        __syncthreads();
        // stage edge features: e = [x_j - x_i (32), x_i (32)]
        for (int u = tid; u < EPI * 64; u += NT) {
            int e_i = u >> 6, c = u & 63;
            int p = pt0 + e_i / K;
            int kk = e_i % K;
            float xi = xb[(size_t)p * 32 + (c & 31)];
            float v;
            if (c < 32) {
                int j = idxb[(size_t)p * K + kk];
                v = xb[(size_t)j * 32 + c] - xi;
            } else {
                v = xi;
            }
            E[e_i * 72 + c] = v;
        }
        __syncthreads();
        // layer 1: 64 -> 128
        float4 acc[4];
        {
            float4 bv = *(const float4*)&ba_s[4 * og];
            #pragma unroll
            for (int i = 0; i < 4; ++i) acc[i] = bv;
        }
        #pragma unroll
        for (int c = 0; c < 64; c += 4) {
            float4 w0 = *(const float4*)&WaT[(c + 0) * 128 + 4 * og];
            float4 w1 = *(const float4*)&WaT[(c + 1) * 128 + 4 * og];
            float4 w2 = *(const float4*)&WaT[(c + 2) * 128 + 4 * og];
            float4 w3 = *(const float4*)&WaT[(c + 3) * 128 + 4 * og];
            #pragma unroll
            for (int i = 0; i < 4; ++i) {
                float4 ev = *(const float4*)&E[(4 * eg + i) * 72 + c];
                acc[i].x += w0.x * ev.x + w1.x * ev.y + w2.x * ev.z + w3.x * ev.w;
                acc[i].y += w0.y * ev.x + w1.y * ev.y + w2.y * ev.z + w3.y * ev.w;
                acc[i].z += w0.z * ev.x + w1.z * ev.y + w2.z * ev.z + w3.z * ev.w;
                acc[i].w += w0.w * ev.x + w1.w * ev.y + w2.w * ev.z + w3.w * ev.w;
            }
        }
        #pragma unroll
        for (int i = 0; i < 4; ++i)
            *(float4*)&H1[(4 * eg + i) * 132 + 4 * og] = lrelu4(acc[i]);
        __syncthreads();
        // layer 2: 128 -> 128
        float4 acc2[4];
        {
            float4 bv = *(const float4*)&bb_s[4 * og];
            #pragma unroll
            for (int i = 0; i < 4; ++i) acc2[i] = bv;
        }
        #pragma unroll
        for (int c = 0; c < 128; c += 4) {
            float4 w0 = *(const float4*)&WbT[(c + 0) * 128 + 4 * og];
            float4 w1 = *(const float4*)&WbT[(c + 1) * 128 + 4 * og];
            float4 w2 = *(const float4*)&WbT[(c + 2) * 128 + 4 * og];
            float4 w3 = *(const float4*)&WbT[(c + 3) * 128 + 4 * og];
            #pragma unroll
            for (int i = 0; i < 4; ++i) {
                float4 ev = *(const float4*)&H1[(4 * eg + i) * 132 + c];
                acc2[i].x += w0.x * ev.x + w1.x * ev.y + w2.x * ev.z + w3.x * ev.w;
                acc2[i].y += w0.y * ev.x + w1.y * ev.y + w2.y * ev.z + w3.y * ev.w;
                acc2[i].z += w0.z * ev.x + w1.z * ev.y + w2.z * ev.z + w3.z * ev.w;
                acc2[i].w += w0.w * ev.x + w1.w * ev.y + w2.w * ev.z + w3.w * ev.w;
            }
        }
        // leaky + max over this thread's 4 edges
        float4 m = lrelu4(acc2[0]);
        m = fmax4(m, lrelu4(acc2[1]));
        m = fmax4(m, lrelu4(acc2[2]));
        m = fmax4(m, lrelu4(acc2[3]));
        if constexpr (K == 4) {
            // thread's 4 edges == all k edges of point (pt0+eg)
            *(float4*)&yb[((size_t)(pt0 + eg)) * 128 + 4 * og] = m;
        } else {
            *(float4*)&P[eg * 128 + 4 * og] = m;
            __syncthreads();
            for (int u = tid; u < PI * 128; u += NT) {
                int p = u >> 7, o = u & 127;
                float v = fmaxf(fmaxf(P[(3 * p) * 128 + o], P[(3 * p + 1) * 128 + o]),
                                P[(3 * p + 2) * 128 + o]);
                yb[((size_t)(pt0 + p)) * 128 + o] = v;
            }
        }
    }
}

// ---------------- conv_mid: y [B*N,128] -> x1 [B*N,32], leaky ----------------
__global__ void k_conv_mid(const float* __restrict__ xin, const float* __restrict__ W,
                           const float* __restrict__ bias, float* __restrict__ out) {
    int gid = blockIdx.x * blockDim.x + threadIdx.x;
    const float4* row = (const float4*)(xin + (size_t)gid * 128);
    float acc[32];
    #pragma unroll
    for (int o = 0; o < 32; ++o) acc[o] = bias[o];
    #pragma unroll 2
    for (int c4 = 0; c4 < 32; ++c4) {
        float4 v = row[c4];
        #pragma unroll
        for (int o = 0; o < 32; ++o) {
            const float* w = W + o * 128 + c4 * 4;   // uniform -> s_load
            acc[o] += v.x * w[0] + v.y * w[1] + v.z * w[2] + v.w * w[3];
        }
    }
    float4* op = (float4*)(out + (size_t)gid * 32);
    #pragma unroll
    for (int o4 = 0; o4 < 8; ++o4)
        op[o4] = make_float4(lrelu(acc[o4 * 4]), lrelu(acc[o4 * 4 + 1]),
                             lrelu(acc[o4 * 4 + 2]), lrelu(acc[o4 * 4 + 3]));
}

// ---------------- decoder: y1 [B*N,128] -> out [B*N,12] ----------------
__global__ void k_decoder(const float* __restrict__ xin,
                          const float* __restrict__ W0, const float* __restrict__ b0,
                          const float* __restrict__ W1, const float* __restrict__ b1,
                          const float* __restrict__ W2, const float* __restrict__ b2,
                          float* __restrict__ out) {
    int gid = blockIdx.x * blockDim.x + threadIdx.x;
    const float4* row = (const float4*)(xin + (size_t)gid * 128);
    float h0[6];
    #pragma unroll
    for (int o = 0; o < 6; ++o) h0[o] = b0[o];
    #pragma unroll 4
    for (int c4 = 0; c4 < 32; ++c4) {
        float4 v = row[c4];
        #pragma unroll
        for (int o = 0; o < 6; ++o) {
            const float* w = W0 + o * 128 + c4 * 4;
            h0[o] += v.x * w[0] + v.y * w[1] + v.z * w[2] + v.w * w[3];
        }
    }
    #pragma unroll
    for (int o = 0; o < 6; ++o) h0[o] = lrelu(h0[o]);
    float h1[12];
    #pragma unroll
    for (int o = 0; o < 12; ++o) {
        float a = b1[o];
        #pragma unroll
        for (int j = 0; j < 6; ++j) a += W1[o * 6 + j] * h0[j];
        h1[o] = lrelu(a);
    }
    float* op = out + (size_t)gid * 12;
    #pragma unroll
    for (int o = 0; o < 12; ++o) {
        float a = b2[o];
        #pragma unroll
        for (int j = 0; j < 12; ++j) a += W2[o * 12 + j] * h1[j];
        op[o] = a;
    }
}

extern "C" void kernel_launch(void* const* d_in, const int* in_sizes, int n_in,
                              void* d_out, int out_size, void* d_ws, size_t ws_size,
                              hipStream_t stream) {
    const float* feature = (const float*)d_in[0];
    const float* Wc0 = (const float*)d_in[1];
    const float* bc0 = (const float*)d_in[2];
    const float* We0a = (const float*)d_in[3];
    const float* be0a = (const float*)d_in[4];
    const float* We0b = (const float*)d_in[5];
    const float* be0b = (const float*)d_in[6];
    const float* Wc1 = (const float*)d_in[7];
    const float* bc1 = (const float*)d_in[8];
    const float* We1a = (const float*)d_in[9];
    const float* be1a = (const float*)d_in[10];
    const float* We1b = (const float*)d_in[11];
    const float* be1b = (const float*)d_in[12];
    const float* Wd0 = (const float*)d_in[13];
    const float* bd0 = (const float*)d_in[14];
    const float* Wd1 = (const float*)d_in[15];
    const float* bd1 = (const float*)d_in[16];
    const float* Wd2 = (const float*)d_in[17];
    const float* bd2 = (const float*)d_in[18];
    float* out = (float*)d_out;

    // workspace layout (~21 MB)
    float* x0 = (float*)d_ws;                       // 16384*32
    int* idx0 = (int*)(x0 + 16384 * 32);            // 16384*12
    float* y0 = (float*)(idx0 + 16384 * 12);        // 16384*128
    float* x1 = y0 + (size_t)16384 * 128;           // 16384*32
    int* idx1 = (int*)(x1 + 16384 * 32);            // 16384*4
    float* y1 = (float*)(idx1 + 16384 * 4);         // 16384*128

    k_conv_in<<<64, 256, 0, stream>>>(feature, Wc0, bc0, x0);
    k_knn<12><<<256, 256, 0, stream>>>(x0, idx0);
    k_edgeconv<12><<<256, 192, 0, stream>>>(x0, idx0, We0a, be0a, We0b, be0b, y0);
    k_conv_mid<<<64, 256, 0, stream>>>(y0, Wc1, bc1, x1);
    k_knn<4><<<256, 256, 0, stream>>>(x1, idx1);
    k_edgeconv<4><<<256, 256, 0, stream>>>(x1, idx1, We1a, be1a, We1b, be1b, y1);
    k_decoder<<<64, 256, 0, stream>>>(y1, Wd0, bd0, Wd1, bd1, Wd2, bd2, out);
}

// Round 2
// 2757.066 us; speedup vs baseline: 2.5275x; 2.5275x over previous
//
#include <hip/hip_runtime.h>

#define NPTS 8192
#define NB 2

__device__ __forceinline__ float lrelu(float x) { return x > 0.f ? x : 0.2f * x; }
__device__ __forceinline__ float4 lrelu4(float4 a) {
    return make_float4(lrelu(a.x), lrelu(a.y), lrelu(a.z), lrelu(a.w));
}
__device__ __forceinline__ float4 fmax4(float4 a, float4 b) {
    return make_float4(fmaxf(a.x, b.x), fmaxf(a.y, b.y), fmaxf(a.z, b.z), fmaxf(a.w, b.w));
}

// ---------------- prep: transpose edge-MLP weights into ws ----------------
// out: WaT0[64x128 as c*128+o], WbT0[128x128], WaT1, WbT1  (total 49152 floats)
__global__ void k_transpose_w(const float* __restrict__ Wa0, const float* __restrict__ Wb0,
                              const float* __restrict__ Wa1, const float* __restrict__ Wb1,
                              float* __restrict__ out) {
    int t = blockIdx.x * 256 + threadIdx.x;
    if (t < 8192)       out[t] = Wa0[(t & 127) * 64 + (t >> 7)];
    else if (t < 24576) { int i = t - 8192;  out[t] = Wb0[(i & 127) * 128 + (i >> 7)]; }
    else if (t < 32768) { int i = t - 24576; out[t] = Wa1[(i & 127) * 64 + (i >> 7)]; }
    else if (t < 49152) { int i = t - 32768; out[t] = Wb1[(i & 127) * 128 + (i >> 7)]; }
}

// ---------------- conv_in: feature [B,128,N] -> x0 [B*N,32], leaky ----------------
__global__ void k_conv_in(const float* __restrict__ f, const float* __restrict__ W,
                          const float* __restrict__ bias, float* __restrict__ out) {
    int gid = blockIdx.x * blockDim.x + threadIdx.x;   // over B*N
    int b = gid >> 13, n = gid & (NPTS - 1);
    const float* fb = f + ((size_t)b << 20) + n;       // b*128*8192
    float acc[32];
    #pragma unroll
    for (int o = 0; o < 32; ++o) acc[o] = bias[o];
    #pragma unroll 4
    for (int c = 0; c < 128; ++c) {
        float xc = fb[(size_t)c * NPTS];               // coalesced across lanes
        #pragma unroll
        for (int o = 0; o < 32; ++o) acc[o] += xc * W[o * 128 + c];  // uniform -> s_load
    }
    float4* op = (float4*)(out + (size_t)gid * 32);
    #pragma unroll
    for (int o4 = 0; o4 < 8; ++o4)
        op[o4] = make_float4(lrelu(acc[o4 * 4]), lrelu(acc[o4 * 4 + 1]),
                             lrelu(acc[o4 * 4 + 2]), lrelu(acc[o4 * 4 + 3]));
}

// ---------------- kNN: x [B*N,32] -> idx [B,N,K] ----------------
template <int K>
__global__ __launch_bounds__(256, 2) void k_knn(const float* __restrict__ x, int* __restrict__ idx_out) {
    __shared__ __align__(16) float Xt[128 * 32];
    __shared__ float sqt[128];
    __shared__ float cd[64 * 8 * K];
    __shared__ int ci[64 * 8 * K];

    int tid = threadIdx.x;
    int s = tid >> 5, q = tid & 31;
    int b = blockIdx.x >> 7;                // / (8192/64)
    int pbase = (blockIdx.x & 127) << 6;    // *64
    const float* xb = x + ((size_t)b * NPTS) * 32;

    int p0 = pbase + q, p1 = pbase + q + 32;
    float4 xi0v[8], xi1v[8];
    {
        const float4* r0 = (const float4*)(xb + (size_t)p0 * 32);
        const float4* r1 = (const float4*)(xb + (size_t)p1 * 32);
        #pragma unroll
        for (int u = 0; u < 8; ++u) { xi0v[u] = r0[u]; xi1v[u] = r1[u]; }
    }
    float bd0[K], bd1[K];
    int bi0[K], bi1[K];
    #pragma unroll
    for (int r = 0; r < K; ++r) { bd0[r] = 1e30f; bd1[r] = 1e30f; bi0[r] = 0; bi1[r] = 0; }

    for (int t = 0; t < NPTS / 128; ++t) {
        __syncthreads();
        const float4* src = (const float4*)(xb + (size_t)t * 128 * 32);
        float4* dst = (float4*)Xt;
        float ssq = 0.f;
        #pragma unroll
        for (int u = 0; u < 4; ++u) {
            float4 v = src[tid * 4 + u];
            dst[tid * 4 + u] = v;
            ssq += v.x * v.x + v.y * v.y + v.z * v.z + v.w * v.w;
        }
        float so = __shfl_xor(ssq, 1);
        if ((tid & 1) == 0) sqt[tid >> 1] = ssq + so;
        __syncthreads();
        #pragma unroll 2
        for (int m = 0; m < 16; ++m) {
            int jj = s + (m << 3);
            const float4* xr = (const float4*)(Xt + jj * 32);
            float dot0 = 0.f, dot1 = 0.f;
            #pragma unroll
            for (int c = 0; c < 8; ++c) {
                float4 xv = xr[c];
                float4 a = xi0v[c];
                float4 e = xi1v[c];
                dot0 += xv.x * a.x + xv.y * a.y + xv.z * a.z + xv.w * a.w;
                dot1 += xv.x * e.x + xv.y * e.y + xv.z * e.z + xv.w * e.w;
            }
            float sj = sqt[jj];
            float d0 = sj - 2.f * dot0;   // rank key (sq_i is a const offset per i)
            float d1 = sj - 2.f * dot1;
            int j = (t << 7) + jj;
            if (d0 < bd0[K - 1]) {        // sorted insertion, all static indices
                float dd = d0; int ji = j;
                #pragma unroll
                for (int r = 0; r < K; ++r) {
                    if (dd < bd0[r]) {
                        float tf = bd0[r]; bd0[r] = dd; dd = tf;
                        int ti = bi0[r]; bi0[r] = ji; ji = ti;
                    }
                }
            }
            if (d1 < bd1[K - 1]) {
                float dd = d1; int ji = j;
                #pragma unroll
                for (int r = 0; r < K; ++r) {
                    if (dd < bd1[r]) {
                        float tf = bd1[r]; bd1[r] = dd; dd = tf;
                        int ti = bi1[r]; bi1[r] = ji; ji = ti;
                    }
                }
            }
        }
    }
    __syncthreads();
    #pragma unroll
    for (int r = 0; r < K; ++r) {
        cd[(q * 8 + s) * K + r] = bd0[r];
        ci[(q * 8 + s) * K + r] = bi0[r];
        cd[((q + 32) * 8 + s) * K + r] = bd1[r];
        ci[((q + 32) * 8 + s) * K + r] = bi1[r];
    }
    __syncthreads();
    if (tid < 64) {   // merge 8 segment lists per point, (dist, idx) lexicographic
        float* md = cd + tid * 8 * K;
        int* mi = ci + tid * 8 * K;
        int* op = idx_out + ((size_t)b * NPTS + pbase + tid) * K;
        for (int r = 0; r < K; ++r) {
            float best = 1e30f; int bj = 0x7fffffff; int bs = 0;
            for (int u = 0; u < 8 * K; ++u) {
                float dv = md[u]; int jv = mi[u];
                if (dv < best || (dv == best && jv < bj)) { best = dv; bj = jv; bs = u; }
            }
            md[bs] = 1e30f;
            op[r] = bj;
        }
    }
}

// ---------------- EdgeConv: x [B*N,32] + idx + pre-transposed weights -> y [B*N,128] ----------------
// K=12: 384 threads (12 groups x 32 lanes), 4 points/iter. K=4: 512 threads, 16 points/iter.
template <int K>
__global__ __launch_bounds__((K == 12) ? 384 : 512, 1)
void k_edgeconv(const float* __restrict__ x, const int* __restrict__ idx,
                const float* __restrict__ WaTg, const float* __restrict__ ba,
                const float* __restrict__ WbTg, const float* __restrict__ bb,
                float* __restrict__ y) {
    constexpr int EG = (K == 12) ? 12 : 16;   // edge-groups of 4 edges
    constexpr int NT = 32 * EG;               // 384 or 512 threads
    constexpr int PI = (4 * EG) / K;          // points per iteration: 4 or 16
    constexpr int EPI = PI * K;               // edges per iteration: 48 or 64
    constexpr int PPB = 64;                   // points per block

    __shared__ __align__(16) float WaT[64 * 128];
    __shared__ __align__(16) float WbT[128 * 128];
    __shared__ __align__(16) float ba_s[128];
    __shared__ __align__(16) float bb_s[128];
    __shared__ __align__(16) float E[EPI * 72];
    __shared__ __align__(16) float H1[EPI * 132];
    __shared__ __align__(16) float P[(K == 12) ? 12 * 128 : 4];

    int tid = threadIdx.x;
    {   // coalesced float4 staging of pre-transposed weights
        const float4* sa = (const float4*)WaTg;
        const float4* sb = (const float4*)WbTg;
        float4* da = (float4*)WaT;
        float4* db = (float4*)WbT;
        for (int i = tid; i < 64 * 128 / 4; i += NT) da[i] = sa[i];
        for (int i = tid; i < 128 * 128 / 4; i += NT) db[i] = sb[i];
        if (tid < 128) { ba_s[tid] = ba[tid]; bb_s[tid] = bb[tid]; }
    }

    int b = blockIdx.x >> 7;
    int pbase = (blockIdx.x & 127) * PPB;
    const float* xb = x + ((size_t)b * NPTS) * 32;
    const int* idxb = idx + ((size_t)b * NPTS) * K;
    float* yb = y + ((size_t)b * NPTS) * 128;

    int og = tid & 31, eg = tid >> 5;

    for (int it = 0; it < PPB / PI; ++it) {
        int pt0 = pbase + it * PI;
        __syncthreads();
        // stage edge features (float4): e = [x_j - x_i (32), x_i (32)]
        for (int u = tid; u < EPI * 16; u += NT) {
            int e_i = u >> 4, c4 = u & 15;
            int p = pt0 + e_i / K;
            int kk = e_i % K;
            const float4* xip = (const float4*)(xb + (size_t)p * 32);
            float4 v;
            if (c4 < 8) {
                int j = idxb[(size_t)p * K + kk];
                float4 xj = ((const float4*)(xb + (size_t)j * 32))[c4];
                float4 xi = xip[c4];
                v = make_float4(xj.x - xi.x, xj.y - xi.y, xj.z - xi.z, xj.w - xi.w);
            } else {
                v = xip[c4 - 8];
            }
            *(float4*)&E[e_i * 72 + 4 * c4] = v;
        }
        __syncthreads();
        // layer 1: 64 -> 128 (4 outputs x 4 edges per thread)
        float4 acc[4];
        {
            float4 bv = *(const float4*)&ba_s[4 * og];
            #pragma unroll
            for (int i = 0; i < 4; ++i) acc[i] = bv;
        }
        #pragma unroll
        for (int c = 0; c < 64; c += 4) {
            float4 w0 = *(const float4*)&WaT[(c + 0) * 128 + 4 * og];
            float4 w1 = *(const float4*)&WaT[(c + 1) * 128 + 4 * og];
            float4 w2 = *(const float4*)&WaT[(c + 2) * 128 + 4 * og];
            float4 w3 = *(const float4*)&WaT[(c + 3) * 128 + 4 * og];
            #pragma unroll
            for (int i = 0; i < 4; ++i) {
                float4 ev = *(const float4*)&E[(4 * eg + i) * 72 + c];
                acc[i].x += w0.x * ev.x + w1.x * ev.y + w2.x * ev.z + w3.x * ev.w;
                acc[i].y += w0.y * ev.x + w1.y * ev.y + w2.y * ev.z + w3.y * ev.w;
                acc[i].z += w0.z * ev.x + w1.z * ev.y + w2.z * ev.z + w3.z * ev.w;
                acc[i].w += w0.w * ev.x + w1.w * ev.y + w2.w * ev.z + w3.w * ev.w;
            }
        }
        #pragma unroll
        for (int i = 0; i < 4; ++i)
            *(float4*)&H1[(4 * eg + i) * 132 + 4 * og] = lrelu4(acc[i]);
        __syncthreads();
        // layer 2: 128 -> 128
        float4 acc2[4];
        {
            float4 bv = *(const float4*)&bb_s[4 * og];
            #pragma unroll
            for (int i = 0; i < 4; ++i) acc2[i] = bv;
        }
        #pragma unroll
        for (int c = 0; c < 128; c += 4) {
            float4 w0 = *(const float4*)&WbT[(c + 0) * 128 + 4 * og];
            float4 w1 = *(const float4*)&WbT[(c + 1) * 128 + 4 * og];
            float4 w2 = *(const float4*)&WbT[(c + 2) * 128 + 4 * og];
            float4 w3 = *(const float4*)&WbT[(c + 3) * 128 + 4 * og];
            #pragma unroll
            for (int i = 0; i < 4; ++i) {
                float4 ev = *(const float4*)&H1[(4 * eg + i) * 132 + c];
                acc2[i].x += w0.x * ev.x + w1.x * ev.y + w2.x * ev.z + w3.x * ev.w;
                acc2[i].y += w0.y * ev.x + w1.y * ev.y + w2.y * ev.z + w3.y * ev.w;
                acc2[i].z += w0.z * ev.x + w1.z * ev.y + w2.z * ev.z + w3.z * ev.w;
                acc2[i].w += w0.w * ev.x + w1.w * ev.y + w2.w * ev.z + w3.w * ev.w;
            }
        }
        // leaky + max over this thread's 4 edges (all 4 belong to one point)
        float4 m = lrelu4(acc2[0]);
        m = fmax4(m, lrelu4(acc2[1]));
        m = fmax4(m, lrelu4(acc2[2]));
        m = fmax4(m, lrelu4(acc2[3]));
        if constexpr (K == 4) {
            *(float4*)&yb[((size_t)(pt0 + eg)) * 128 + 4 * og] = m;
        } else {
            *(float4*)&P[eg * 128 + 4 * og] = m;
            __syncthreads();
            for (int u = tid; u < PI * 128; u += NT) {
                int p = u >> 7, o = u & 127;
                float v = fmaxf(fmaxf(P[(3 * p) * 128 + o], P[(3 * p + 1) * 128 + o]),
                                P[(3 * p + 2) * 128 + o]);
                yb[((size_t)(pt0 + p)) * 128 + o] = v;
            }
        }
    }
}

// ---------------- conv_mid: y [B*N,128] -> x1 [B*N,32], leaky ----------------
__global__ void k_conv_mid(const float* __restrict__ xin, const float* __restrict__ W,
                           const float* __restrict__ bias, float* __restrict__ out) {
    int gid = blockIdx.x * blockDim.x + threadIdx.x;
    const float4* row = (const float4*)(xin + (size_t)gid * 128);
    float acc[32];
    #pragma unroll
    for (int o = 0; o < 32; ++o) acc[o] = bias[o];
    #pragma unroll 2
    for (int c4 = 0; c4 < 32; ++c4) {
        float4 v = row[c4];
        #pragma unroll
        for (int o = 0; o < 32; ++o) {
            const float* w = W + o * 128 + c4 * 4;   // uniform -> s_load
            acc[o] += v.x * w[0] + v.y * w[1] + v.z * w[2] + v.w * w[3];
        }
    }
    float4* op = (float4*)(out + (size_t)gid * 32);
    #pragma unroll
    for (int o4 = 0; o4 < 8; ++o4)
        op[o4] = make_float4(lrelu(acc[o4 * 4]), lrelu(acc[o4 * 4 + 1]),
                             lrelu(acc[o4 * 4 + 2]), lrelu(acc[o4 * 4 + 3]));
}

// ---------------- decoder: y1 [B*N,128] -> out [B*N,12] ----------------
__global__ void k_decoder(const float* __restrict__ xin,
                          const float* __restrict__ W0, const float* __restrict__ b0,
                          const float* __restrict__ W1, const float* __restrict__ b1,
                          const float* __restrict__ W2, const float* __restrict__ b2,
                          float* __restrict__ out) {
    int gid = blockIdx.x * blockDim.x + threadIdx.x;
    const float4* row = (const float4*)(xin + (size_t)gid * 128);
    float h0[6];
    #pragma unroll
    for (int o = 0; o < 6; ++o) h0[o] = b0[o];
    #pragma unroll 4
    for (int c4 = 0; c4 < 32; ++c4) {
        float4 v = row[c4];
        #pragma unroll
        for (int o = 0; o < 6; ++o) {
            const float* w = W0 + o * 128 + c4 * 4;
            h0[o] += v.x * w[0] + v.y * w[1] + v.z * w[2] + v.w * w[3];
        }
    }
    #pragma unroll
    for (int o = 0; o < 6; ++o) h0[o] = lrelu(h0[o]);
    float h1[12];
    #pragma unroll
    for (int o = 0; o < 12; ++o) {
        float a = b1[o];
        #pragma unroll
        for (int j = 0; j < 6; ++j) a += W1[o * 6 + j] * h0[j];
        h1[o] = lrelu(a);
    }
    float* op = out + (size_t)gid * 12;
    #pragma unroll
    for (int o = 0; o < 12; ++o) {
        float a = b2[o];
        #pragma unroll
        for (int j = 0; j < 12; ++j) a += W2[o * 12 + j] * h1[j];
        op[o] = a;
    }
}

extern "C" void kernel_launch(void* const* d_in, const int* in_sizes, int n_in,
                              void* d_out, int out_size, void* d_ws, size_t ws_size,
                              hipStream_t stream) {
    const float* feature = (const float*)d_in[0];
    const float* Wc0 = (const float*)d_in[1];
    const float* bc0 = (const float*)d_in[2];
    const float* We0a = (const float*)d_in[3];
    const float* be0a = (const float*)d_in[4];
    const float* We0b = (const float*)d_in[5];
    const float* be0b = (const float*)d_in[6];
    const float* Wc1 = (const float*)d_in[7];
    const float* bc1 = (const float*)d_in[8];
    const float* We1a = (const float*)d_in[9];
    const float* be1a = (const float*)d_in[10];
    const float* We1b = (const float*)d_in[11];
    const float* be1b = (const float*)d_in[12];
    const float* Wd0 = (const float*)d_in[13];
    const float* bd0 = (const float*)d_in[14];
    const float* Wd1 = (const float*)d_in[15];
    const float* bd1 = (const float*)d_in[16];
    const float* Wd2 = (const float*)d_in[17];
    const float* bd2 = (const float*)d_in[18];
    float* out = (float*)d_out;

    // workspace layout (~21.2 MB)
    float* x0 = (float*)d_ws;                       // 16384*32
    int* idx0 = (int*)(x0 + 16384 * 32);            // 16384*12
    float* y0 = (float*)(idx0 + 16384 * 12);        // 16384*128
    float* x1 = y0 + (size_t)16384 * 128;           // 16384*32
    int* idx1 = (int*)(x1 + 16384 * 32);            // 16384*4
    float* y1 = (float*)(idx1 + 16384 * 4);         // 16384*128
    float* wT = y1 + (size_t)16384 * 128;           // 49152 transposed weights
    float* WaT0 = wT;
    float* WbT0 = wT + 8192;
    float* WaT1 = wT + 24576;
    float* WbT1 = wT + 32768;

    k_transpose_w<<<192, 256, 0, stream>>>(We0a, We0b, We1a, We1b, wT);
    k_conv_in<<<64, 256, 0, stream>>>(feature, Wc0, bc0, x0);
    k_knn<12><<<256, 256, 0, stream>>>(x0, idx0);
    k_edgeconv<12><<<256, 384, 0, stream>>>(x0, idx0, WaT0, be0a, WbT0, be0b, y0);
    k_conv_mid<<<64, 256, 0, stream>>>(y0, Wc1, bc1, x1);
    k_knn<4><<<256, 256, 0, stream>>>(x1, idx1);
    k_edgeconv<4><<<256, 512, 0, stream>>>(x1, idx1, WaT1, be1a, WbT1, be1b, y1);
    k_decoder<<<64, 256, 0, stream>>>(y1, Wd0, bd0, Wd1, bd1, Wd2, bd2, out);
}

// Round 3
// 2358.465 us; speedup vs baseline: 2.9547x; 1.1690x over previous
//
#include <hip/hip_runtime.h>

#define NPTS 8192
#define NB 2

__device__ __forceinline__ float lrelu(float x) { return x > 0.f ? x : 0.2f * x; }
__device__ __forceinline__ float4 lrelu4(float4 a) {
    return make_float4(lrelu(a.x), lrelu(a.y), lrelu(a.z), lrelu(a.w));
}
__device__ __forceinline__ float4 fmax4(float4 a, float4 b) {
    return make_float4(fmaxf(a.x, b.x), fmaxf(a.y, b.y), fmaxf(a.z, b.z), fmaxf(a.w, b.w));
}

// ---------------- prep: transpose edge-MLP weights into ws ----------------
__global__ void k_transpose_w(const float* __restrict__ Wa0, const float* __restrict__ Wb0,
                              const float* __restrict__ Wa1, const float* __restrict__ Wb1,
                              float* __restrict__ out) {
    int t = blockIdx.x * 256 + threadIdx.x;
    if (t < 8192)       out[t] = Wa0[(t & 127) * 64 + (t >> 7)];
    else if (t < 24576) { int i = t - 8192;  out[t] = Wb0[(i & 127) * 128 + (i >> 7)]; }
    else if (t < 32768) { int i = t - 24576; out[t] = Wa1[(i & 127) * 64 + (i >> 7)]; }
    else if (t < 49152) { int i = t - 32768; out[t] = Wb1[(i & 127) * 128 + (i >> 7)]; }
}

// ---------------- conv_in: feature [B,128,N] -> x0 [B*N,32], leaky ----------------
__global__ void k_conv_in(const float* __restrict__ f, const float* __restrict__ W,
                          const float* __restrict__ bias, float* __restrict__ out) {
    int gid = blockIdx.x * blockDim.x + threadIdx.x;   // over B*N
    int b = gid >> 13, n = gid & (NPTS - 1);
    const float* fb = f + ((size_t)b << 20) + n;       // b*128*8192
    float acc[32];
    #pragma unroll
    for (int o = 0; o < 32; ++o) acc[o] = bias[o];
    #pragma unroll 4
    for (int c = 0; c < 128; ++c) {
        float xc = fb[(size_t)c * NPTS];               // coalesced across lanes
        #pragma unroll
        for (int o = 0; o < 32; ++o) acc[o] += xc * W[o * 128 + c];  // uniform -> s_load
    }
    float4* op = (float4*)(out + (size_t)gid * 32);
    #pragma unroll
    for (int o4 = 0; o4 < 8; ++o4)
        op[o4] = make_float4(lrelu(acc[o4 * 4]), lrelu(acc[o4 * 4 + 1]),
                             lrelu(acc[o4 * 4 + 2]), lrelu(acc[o4 * 4 + 3]));
}

// ---------------- kNN candidates: x [B*N,32] -> cand (top-K per j-segment) ----------------
// 1 i-point per thread; whole block scans the same j (broadcast LDS reads).
// Grid: NB * (NPTS/256) * JS blocks. Block tid = point pbase+tid, j-range jseg*(NPTS/JS).
template <int K, int JS>
__global__ __launch_bounds__(256, 4) void k_knn_cand(const float* __restrict__ x,
                                                     float* __restrict__ cand_d,
                                                     int* __restrict__ cand_i) {
    __shared__ __align__(16) float Xt[128 * 32];
    __shared__ float sqt[128];
    constexpr int JR = NPTS / JS;           // j-range per segment (1024 for JS=8)
    constexpr int BPB = (NPTS / 256) * JS;  // blocks per batch (256)

    int tid = threadIdx.x;
    int bid = blockIdx.x;
    int b = bid / BPB;
    int r0 = bid - b * BPB;
    int itile = r0 / JS;
    int jseg = r0 - itile * JS;

    const float* xb = x + ((size_t)b * NPTS) * 32;
    int pt = itile * 256 + tid;

    float4 xi[8];
    {
        const float4* xrow = (const float4*)(xb + (size_t)pt * 32);
        #pragma unroll
        for (int u = 0; u < 8; ++u) xi[u] = xrow[u];
    }
    float bd[K]; int bi[K];
    #pragma unroll
    for (int r = 0; r < K; ++r) { bd[r] = 1e30f; bi[r] = 0; }

    int jbase0 = jseg * JR;
    for (int t = 0; t < JR / 128; ++t) {
        int jbase = jbase0 + t * 128;
        __syncthreads();
        // contiguous staging: float4 #v of the tile (row v>>3, chunk v&7)
        const float4* gsrc = (const float4*)(xb + (size_t)jbase * 32);
        float4* dst = (float4*)Xt;
        float ss[4];
        #pragma unroll
        for (int u = 0; u < 4; ++u) {
            float4 v = gsrc[u * 256 + tid];
            dst[u * 256 + tid] = v;
            ss[u] = v.x * v.x + v.y * v.y + v.z * v.z + v.w * v.w;
        }
        #pragma unroll
        for (int u = 0; u < 4; ++u) {       // reduce the 8 chunks of each row (lanes tid&7)
            ss[u] += __shfl_xor(ss[u], 1);
            ss[u] += __shfl_xor(ss[u], 2);
            ss[u] += __shfl_xor(ss[u], 4);
        }
        if ((tid & 7) == 0) {
            #pragma unroll
            for (int u = 0; u < 4; ++u) sqt[(tid >> 3) + u * 32] = ss[u];
        }
        __syncthreads();
        #pragma unroll 2
        for (int jj = 0; jj < 128; ++jj) {
            const float4* xr = (const float4*)(Xt + jj * 32);   // broadcast (same addr all lanes)
            float da = 0.f, db = 0.f;
            #pragma unroll
            for (int c = 0; c < 8; c += 2) {
                float4 v0 = xr[c], v1 = xr[c + 1];
                da += v0.x * xi[c].x + v0.y * xi[c].y + v0.z * xi[c].z + v0.w * xi[c].w;
                db += v1.x * xi[c + 1].x + v1.y * xi[c + 1].y + v1.z * xi[c + 1].z + v1.w * xi[c + 1].w;
            }
            float d = sqt[jj] - 2.f * (da + db);   // rank key (sq_i const offset per i)
            if (d < bd[K - 1]) {                   // sorted insertion, static indices
                int j = jbase + jj;
                float dd = d; int ji = j;
                #pragma unroll
                for (int r = 0; r < K; ++r) {
                    if (dd < bd[r]) {
                        float tf = bd[r]; bd[r] = dd; dd = tf;
                        int ti = bi[r]; bi[r] = ji; ji = ti;
                    }
                }
            }
        }
    }
    size_t base = ((size_t)jseg * (NB * NPTS) + (size_t)b * NPTS + pt) * K;
    #pragma unroll
    for (int r = 0; r < K; ++r) { cand_d[base + r] = bd[r]; cand_i[base + r] = bi[r]; }
}

// ---------------- merge JS candidate lists -> final idx [B*N, K] ----------------
template <int K, int JS>
__global__ void k_knn_merge(const float* __restrict__ cand_d, const int* __restrict__ cand_i,
                            int* __restrict__ idx_out) {
    constexpr int M = JS * K;               // 96 or 32
    __shared__ float md[64 * (M + 1)];      // stride M+1 (odd) -> 2-way max conflicts
    __shared__ int   mi[64 * (M + 1)];
    int tid = threadIdx.x;                  // 64 threads
    int pbase = blockIdx.x * 64;            // over NB*NPTS
    for (int v = tid; v < 64 * M; v += 64) {
        int s = v / (64 * K);
        int rem = v - s * 64 * K;           // p*K + r
        int p = rem / K;
        size_t g = ((size_t)s * (NB * NPTS) + pbase + p) * K + (rem - p * K);
        md[p * (M + 1) + s * K + (rem - p * K)] = cand_d[g];
        mi[p * (M + 1) + s * K + (rem - p * K)] = cand_i[g];
    }
    __syncthreads();
    float* rd = md + tid * (M + 1);
    int* ri = mi + tid * (M + 1);
    int* op = idx_out + (size_t)(pbase + tid) * K;
    for (int r = 0; r < K; ++r) {           // (dist, idx) lexicographic selection
        float best = 1e30f; int bj = 0x7fffffff; int bs = 0;
        for (int u = 0; u < M; ++u) {
            float dv = rd[u]; int jv = ri[u];
            if (dv < best || (dv == best && jv < bj)) { best = dv; bj = jv; bs = u; }
        }
        rd[bs] = 1e30f;
        op[r] = bj;
    }
}

// ---------------- EdgeConv: x [B*N,32] + idx + pre-transposed weights -> y [B*N,128] ----------------
template <int K>
__global__ __launch_bounds__((K == 12) ? 384 : 512, 1)
void k_edgeconv(const float* __restrict__ x, const int* __restrict__ idx,
                const float* __restrict__ WaTg, const float* __restrict__ ba,
                const float* __restrict__ WbTg, const float* __restrict__ bb,
                float* __restrict__ y) {
    constexpr int EG = (K == 12) ? 12 : 16;   // edge-groups of 4 edges
    constexpr int NT = 32 * EG;               // 384 or 512 threads
    constexpr int PI = (4 * EG) / K;          // points per iteration: 4 or 16
    constexpr int EPI = PI * K;               // edges per iteration: 48 or 64
    constexpr int PPB = 64;                   // points per block

    __shared__ __align__(16) float WaT[64 * 128];
    __shared__ __align__(16) float WbT[128 * 128];
    __shared__ __align__(16) float ba_s[128];
    __shared__ __align__(16) float bb_s[128];
    __shared__ __align__(16) float E[EPI * 72];
    __shared__ __align__(16) float H1[EPI * 132];
    __shared__ __align__(16) float P[(K == 12) ? 12 * 128 : 4];

    int tid = threadIdx.x;
    {
        const float4* sa = (const float4*)WaTg;
        const float4* sb = (const float4*)WbTg;
        float4* da = (float4*)WaT;
        float4* db = (float4*)WbT;
        for (int i = tid; i < 64 * 128 / 4; i += NT) da[i] = sa[i];
        for (int i = tid; i < 128 * 128 / 4; i += NT) db[i] = sb[i];
        if (tid < 128) { ba_s[tid] = ba[tid]; bb_s[tid] = bb[tid]; }
    }

    int b = blockIdx.x >> 7;
    int pbase = (blockIdx.x & 127) * PPB;
    const float* xb = x + ((size_t)b * NPTS) * 32;
    const int* idxb = idx + ((size_t)b * NPTS) * K;
    float* yb = y + ((size_t)b * NPTS) * 128;

    int og = tid & 31, eg = tid >> 5;

    for (int it = 0; it < PPB / PI; ++it) {
        int pt0 = pbase + it * PI;
        __syncthreads();
        for (int u = tid; u < EPI * 16; u += NT) {
            int e_i = u >> 4, c4 = u & 15;
            int p = pt0 + e_i / K;
            int kk = e_i % K;
            const float4* xip = (const float4*)(xb + (size_t)p * 32);
            float4 v;
            if (c4 < 8) {
                int j = idxb[(size_t)p * K + kk];
                float4 xj = ((const float4*)(xb + (size_t)j * 32))[c4];
                float4 xiv = xip[c4];
                v = make_float4(xj.x - xiv.x, xj.y - xiv.y, xj.z - xiv.z, xj.w - xiv.w);
            } else {
                v = xip[c4 - 8];
            }
            *(float4*)&E[e_i * 72 + 4 * c4] = v;
        }
        __syncthreads();
        float4 acc[4];
        {
            float4 bv = *(const float4*)&ba_s[4 * og];
            #pragma unroll
            for (int i = 0; i < 4; ++i) acc[i] = bv;
        }
        #pragma unroll
        for (int c = 0; c < 64; c += 4) {
            float4 w0 = *(const float4*)&WaT[(c + 0) * 128 + 4 * og];
            float4 w1 = *(const float4*)&WaT[(c + 1) * 128 + 4 * og];
            float4 w2 = *(const float4*)&WaT[(c + 2) * 128 + 4 * og];
            float4 w3 = *(const float4*)&WaT[(c + 3) * 128 + 4 * og];
            #pragma unroll
            for (int i = 0; i < 4; ++i) {
                float4 ev = *(const float4*)&E[(4 * eg + i) * 72 + c];
                acc[i].x += w0.x * ev.x + w1.x * ev.y + w2.x * ev.z + w3.x * ev.w;
                acc[i].y += w0.y * ev.x + w1.y * ev.y + w2.y * ev.z + w3.y * ev.w;
                acc[i].z += w0.z * ev.x + w1.z * ev.y + w2.z * ev.z + w3.z * ev.w;
                acc[i].w += w0.w * ev.x + w1.w * ev.y + w2.w * ev.z + w3.w * ev.w;
            }
        }
        #pragma unroll
        for (int i = 0; i < 4; ++i)
            *(float4*)&H1[(4 * eg + i) * 132 + 4 * og] = lrelu4(acc[i]);
        __syncthreads();
        float4 acc2[4];
        {
            float4 bv = *(const float4*)&bb_s[4 * og];
            #pragma unroll
            for (int i = 0; i < 4; ++i) acc2[i] = bv;
        }
        #pragma unroll
        for (int c = 0; c < 128; c += 4) {
            float4 w0 = *(const float4*)&WbT[(c + 0) * 128 + 4 * og];
            float4 w1 = *(const float4*)&WbT[(c + 1) * 128 + 4 * og];
            float4 w2 = *(const float4*)&WbT[(c + 2) * 128 + 4 * og];
            float4 w3 = *(const float4*)&WbT[(c + 3) * 128 + 4 * og];
            #pragma unroll
            for (int i = 0; i < 4; ++i) {
                float4 ev = *(const float4*)&H1[(4 * eg + i) * 132 + c];
                acc2[i].x += w0.x * ev.x + w1.x * ev.y + w2.x * ev.z + w3.x * ev.w;
                acc2[i].y += w0.y * ev.x + w1.y * ev.y + w2.y * ev.z + w3.y * ev.w;
                acc2[i].z += w0.z * ev.x + w1.z * ev.y + w2.z * ev.z + w3.z * ev.w;
                acc2[i].w += w0.w * ev.x + w1.w * ev.y + w2.w * ev.z + w3.w * ev.w;
            }
        }
        float4 m = lrelu4(acc2[0]);
        m = fmax4(m, lrelu4(acc2[1]));
        m = fmax4(m, lrelu4(acc2[2]));
        m = fmax4(m, lrelu4(acc2[3]));
        if constexpr (K == 4) {
            *(float4*)&yb[((size_t)(pt0 + eg)) * 128 + 4 * og] = m;
        } else {
            *(float4*)&P[eg * 128 + 4 * og] = m;
            __syncthreads();
            for (int u = tid; u < PI * 128; u += NT) {
                int p = u >> 7, o = u & 127;
                float v = fmaxf(fmaxf(P[(3 * p) * 128 + o], P[(3 * p + 1) * 128 + o]),
                                P[(3 * p + 2) * 128 + o]);
                yb[((size_t)(pt0 + p)) * 128 + o] = v;
            }
        }
    }
}

// ---------------- conv_mid: y [B*N,128] -> x1 [B*N,32], leaky ----------------
__global__ void k_conv_mid(const float* __restrict__ xin, const float* __restrict__ W,
                           const float* __restrict__ bias, float* __restrict__ out) {
    int gid = blockIdx.x * blockDim.x + threadIdx.x;
    const float4* row = (const float4*)(xin + (size_t)gid * 128);
    float acc[32];
    #pragma unroll
    for (int o = 0; o < 32; ++o) acc[o] = bias[o];
    #pragma unroll 2
    for (int c4 = 0; c4 < 32; ++c4) {
        float4 v = row[c4];
        #pragma unroll
        for (int o = 0; o < 32; ++o) {
            const float* w = W + o * 128 + c4 * 4;   // uniform -> s_load
            acc[o] += v.x * w[0] + v.y * w[1] + v.z * w[2] + v.w * w[3];
        }
    }
    float4* op = (float4*)(out + (size_t)gid * 32);
    #pragma unroll
    for (int o4 = 0; o4 < 8; ++o4)
        op[o4] = make_float4(lrelu(acc[o4 * 4]), lrelu(acc[o4 * 4 + 1]),
                             lrelu(acc[o4 * 4 + 2]), lrelu(acc[o4 * 4 + 3]));
}

// ---------------- decoder: y1 [B*N,128] -> out [B*N,12] ----------------
__global__ void k_decoder(const float* __restrict__ xin,
                          const float* __restrict__ W0, const float* __restrict__ b0,
                          const float* __restrict__ W1, const float* __restrict__ b1,
                          const float* __restrict__ W2, const float* __restrict__ b2,
                          float* __restrict__ out) {
    int gid = blockIdx.x * blockDim.x + threadIdx.x;
    const float4* row = (const float4*)(xin + (size_t)gid * 128);
    float h0[6];
    #pragma unroll
    for (int o = 0; o < 6; ++o) h0[o] = b0[o];
    #pragma unroll 4
    for (int c4 = 0; c4 < 32; ++c4) {
        float4 v = row[c4];
        #pragma unroll
        for (int o = 0; o < 6; ++o) {
            const float* w = W0 + o * 128 + c4 * 4;
            h0[o] += v.x * w[0] + v.y * w[1] + v.z * w[2] + v.w * w[3];
        }
    }
    #pragma unroll
    for (int o = 0; o < 6; ++o) h0[o] = lrelu(h0[o]);
    float h1[12];
    #pragma unroll
    for (int o = 0; o < 12; ++o) {
        float a = b1[o];
        #pragma unroll
        for (int j = 0; j < 6; ++j) a += W1[o * 6 + j] * h0[j];
        h1[o] = lrelu(a);
    }
    float* op = out + (size_t)gid * 12;
    #pragma unroll
    for (int o = 0; o < 12; ++o) {
        float a = b2[o];
        #pragma unroll
        for (int j = 0; j < 12; ++j) a += W2[o * 12 + j] * h1[j];
        op[o] = a;
    }
}

extern "C" void kernel_launch(void* const* d_in, const int* in_sizes, int n_in,
                              void* d_out, int out_size, void* d_ws, size_t ws_size,
                              hipStream_t stream) {
    const float* feature = (const float*)d_in[0];
    const float* Wc0 = (const float*)d_in[1];
    const float* bc0 = (const float*)d_in[2];
    const float* We0a = (const float*)d_in[3];
    const float* be0a = (const float*)d_in[4];
    const float* We0b = (const float*)d_in[5];
    const float* be0b = (const float*)d_in[6];
    const float* Wc1 = (const float*)d_in[7];
    const float* bc1 = (const float*)d_in[8];
    const float* We1a = (const float*)d_in[9];
    const float* be1a = (const float*)d_in[10];
    const float* We1b = (const float*)d_in[11];
    const float* be1b = (const float*)d_in[12];
    const float* Wd0 = (const float*)d_in[13];
    const float* bd0 = (const float*)d_in[14];
    const float* Wd1 = (const float*)d_in[15];
    const float* bd1 = (const float*)d_in[16];
    const float* Wd2 = (const float*)d_in[17];
    const float* bd2 = (const float*)d_in[18];
    float* out = (float*)d_out;

    float* f = (float*)d_ws;
    // static layout (floats), total ~22.2 MB (same footprint as R2)
    float* x0   = f;                       // 524288
    float* x1   = f + 524288;              // 524288
    int*   idx0 = (int*)(f + 1048576);     // 196608
    int*   idx1 = (int*)(f + 1245184);     // 65536
    float* wT   = f + 1310720;             // 49152
    float* y0   = f + 1359872;             // 2097152
    float* y1   = f + 3457024;             // 2097152  (end 5554176)
    // candidate buffers alias the y regions (dead during kNN phases)
    float* c0d  = f + 1359872;             // 1572864 (K=12, JS=8)
    int*   c0i  = (int*)(f + 2932736);     // 1572864 (ends 4505600 < 5554176)
    float* c1d  = f + 1359872;             // 524288 (K=4, JS=8)
    int*   c1i  = (int*)(f + 1884160);     // 524288 (ends 2408448 < y0 end)
    float* WaT0 = wT;
    float* WbT0 = wT + 8192;
    float* WaT1 = wT + 24576;
    float* WbT1 = wT + 32768;

    k_transpose_w<<<192, 256, 0, stream>>>(We0a, We0b, We1a, We1b, wT);
    k_conv_in<<<64, 256, 0, stream>>>(feature, Wc0, bc0, x0);
    k_knn_cand<12, 8><<<512, 256, 0, stream>>>(x0, c0d, c0i);
    k_knn_merge<12, 8><<<256, 64, 0, stream>>>(c0d, c0i, idx0);
    k_edgeconv<12><<<256, 384, 0, stream>>>(x0, idx0, WaT0, be0a, WbT0, be0b, y0);
    k_conv_mid<<<64, 256, 0, stream>>>(y0, Wc1, bc1, x1);
    k_knn_cand<4, 8><<<512, 256, 0, stream>>>(x1, c1d, c1i);
    k_knn_merge<4, 8><<<256, 64, 0, stream>>>(c1d, c1i, idx1);
    k_edgeconv<4><<<256, 512, 0, stream>>>(x1, idx1, WaT1, be1a, WbT1, be1b, y1);
    k_decoder<<<64, 256, 0, stream>>>(y1, Wd0, bd0, Wd1, bd1, Wd2, bd2, out);
}

// Round 4
// 2223.886 us; speedup vs baseline: 3.1335x; 1.0605x over previous
//
#include <hip/hip_runtime.h>

#define NPTS 8192
#define NB 2

__device__ __forceinline__ float lrelu(float x) { return x > 0.f ? x : 0.2f * x; }
__device__ __forceinline__ float4 lrelu4(float4 a) {
    return make_float4(lrelu(a.x), lrelu(a.y), lrelu(a.z), lrelu(a.w));
}
__device__ __forceinline__ float4 fmax4(float4 a, float4 b) {
    return make_float4(fmaxf(a.x, b.x), fmaxf(a.y, b.y), fmaxf(a.z, b.z), fmaxf(a.w, b.w));
}

// ---------------- prep: transpose edge-MLP weights into ws ----------------
__global__ void k_transpose_w(const float* __restrict__ Wa0, const float* __restrict__ Wb0,
                              const float* __restrict__ Wa1, const float* __restrict__ Wb1,
                              float* __restrict__ out) {
    int t = blockIdx.x * 256 + threadIdx.x;
    if (t < 8192)       out[t] = Wa0[(t & 127) * 64 + (t >> 7)];
    else if (t < 24576) { int i = t - 8192;  out[t] = Wb0[(i & 127) * 128 + (i >> 7)]; }
    else if (t < 32768) { int i = t - 24576; out[t] = Wa1[(i & 127) * 64 + (i >> 7)]; }
    else if (t < 49152) { int i = t - 32768; out[t] = Wb1[(i & 127) * 128 + (i >> 7)]; }
}

// ---------------- conv_in: feature [B,128,N] -> x0 [B*N,32], leaky ----------------
__global__ void k_conv_in(const float* __restrict__ f, const float* __restrict__ W,
                          const float* __restrict__ bias, float* __restrict__ out) {
    int gid = blockIdx.x * blockDim.x + threadIdx.x;   // over B*N
    int b = gid >> 13, n = gid & (NPTS - 1);
    const float* fb = f + ((size_t)b << 20) + n;       // b*128*8192
    float acc[32];
    #pragma unroll
    for (int o = 0; o < 32; ++o) acc[o] = bias[o];
    #pragma unroll 4
    for (int c = 0; c < 128; ++c) {
        float xc = fb[(size_t)c * NPTS];               // coalesced across lanes
        #pragma unroll
        for (int o = 0; o < 32; ++o) acc[o] += xc * W[o * 128 + c];  // uniform -> s_load
    }
    float4* op = (float4*)(out + (size_t)gid * 32);
    #pragma unroll
    for (int o4 = 0; o4 < 8; ++o4)
        op[o4] = make_float4(lrelu(acc[o4 * 4]), lrelu(acc[o4 * 4 + 1]),
                             lrelu(acc[o4 * 4 + 2]), lrelu(acc[o4 * 4 + 3]));
}

// ---------------- kNN candidates: x [B*N,32] -> cand (top-K per j-segment) ----------------
// 1 i-point per thread; whole block scans the same j (broadcast LDS reads).
// Top-K kept UNSORTED in registers, replace-max with scalar threshold (no spills).
template <int K, int JS>
__global__ __launch_bounds__(256, 2) void k_knn_cand(const float* __restrict__ x,
                                                     float* __restrict__ cand_d,
                                                     int* __restrict__ cand_i) {
    __shared__ __align__(16) float Xt[128 * 32];
    __shared__ float sqt[128];
    constexpr int JR = NPTS / JS;           // j-range per segment (1024 for JS=8)
    constexpr int BPB = (NPTS / 256) * JS;  // blocks per batch (256)

    int tid = threadIdx.x;
    int bid = blockIdx.x;
    int b = bid / BPB;
    int r0 = bid - b * BPB;
    int itile = r0 / JS;
    int jseg = r0 - itile * JS;

    const float* xb = x + ((size_t)b * NPTS) * 32;
    int pt = itile * 256 + tid;

    float4 xi[8];
    {
        const float4* xrow = (const float4*)(xb + (size_t)pt * 32);
        #pragma unroll
        for (int u = 0; u < 8; ++u) xi[u] = xrow[u];
    }
    float bd[K]; int bi[K];
    #pragma unroll
    for (int r = 0; r < K; ++r) { bd[r] = 1e30f; bi[r] = 0; }
    float thr = 1e30f;   // current worst (max) in the list
    int ts = 0;          // slot holding it

    int jbase0 = jseg * JR;
    for (int t = 0; t < JR / 128; ++t) {
        int jbase = jbase0 + t * 128;
        __syncthreads();
        // contiguous staging: float4 #v of the tile (row v>>3, chunk v&7)
        const float4* gsrc = (const float4*)(xb + (size_t)jbase * 32);
        float4* dst = (float4*)Xt;
        float ss[4];
        #pragma unroll
        for (int u = 0; u < 4; ++u) {
            float4 v = gsrc[u * 256 + tid];
            dst[u * 256 + tid] = v;
            ss[u] = v.x * v.x + v.y * v.y + v.z * v.z + v.w * v.w;
        }
        #pragma unroll
        for (int u = 0; u < 4; ++u) {       // reduce the 8 chunks of each row (lanes tid&7)
            ss[u] += __shfl_xor(ss[u], 1);
            ss[u] += __shfl_xor(ss[u], 2);
            ss[u] += __shfl_xor(ss[u], 4);
        }
        if ((tid & 7) == 0) {
            #pragma unroll
            for (int u = 0; u < 4; ++u) sqt[(tid >> 3) + u * 32] = ss[u];
        }
        __syncthreads();
        #pragma unroll 2
        for (int jj = 0; jj < 128; ++jj) {
            const float4* xr = (const float4*)(Xt + jj * 32);   // broadcast (same addr all lanes)
            float da = 0.f, db = 0.f;
            #pragma unroll
            for (int c = 0; c < 8; c += 2) {
                float4 v0 = xr[c], v1 = xr[c + 1];
                da += v0.x * xi[c].x + v0.y * xi[c].y + v0.z * xi[c].z + v0.w * xi[c].w;
                db += v1.x * xi[c + 1].x + v1.y * xi[c + 1].y + v1.z * xi[c + 1].z + v1.w * xi[c + 1].w;
            }
            float d = sqt[jj] - 2.f * (da + db);   // rank key (sq_i const offset per i)
            // strict < : on distance tie the earlier (lower-index) j stays -> jax tie-break
            if (d < thr) {
                int j = jbase + jj;
                #pragma unroll
                for (int r = 0; r < K; ++r) {      // replace the current max slot
                    bool sel = (r == ts);
                    bd[r] = sel ? d : bd[r];
                    bi[r] = sel ? j : bi[r];
                }
                float m = bd[0]; int mj = bi[0]; int ms = 0;
                #pragma unroll
                for (int r = 1; r < K; ++r) {      // argmax; tie -> evict larger index
                    bool c = (bd[r] > m) || (bd[r] == m && bi[r] > mj);
                    m = c ? bd[r] : m;
                    mj = c ? bi[r] : mj;
                    ms = c ? r : ms;
                }
                thr = m; ts = ms;
            }
        }
    }
    size_t base = ((size_t)jseg * (NB * NPTS) + (size_t)b * NPTS + pt) * K;
    #pragma unroll
    for (int r = 0; r < K; ++r) { cand_d[base + r] = bd[r]; cand_i[base + r] = bi[r]; }
}

// ---------------- merge JS candidate lists -> final idx [B*N, K] ----------------
template <int K, int JS>
__global__ void k_knn_merge(const float* __restrict__ cand_d, const int* __restrict__ cand_i,
                            int* __restrict__ idx_out) {
    constexpr int M = JS * K;               // 96 or 32
    __shared__ float md[64 * (M + 1)];      // stride M+1 (odd) -> 2-way max conflicts
    __shared__ int   mi[64 * (M + 1)];
    int tid = threadIdx.x;                  // 64 threads
    int pbase = blockIdx.x * 64;            // over NB*NPTS
    for (int v = tid; v < 64 * M; v += 64) {
        int s = v / (64 * K);
        int rem = v - s * 64 * K;           // p*K + r
        int p = rem / K;
        size_t g = ((size_t)s * (NB * NPTS) + pbase + p) * K + (rem - p * K);
        md[p * (M + 1) + s * K + (rem - p * K)] = cand_d[g];
        mi[p * (M + 1) + s * K + (rem - p * K)] = cand_i[g];
    }
    __syncthreads();
    float* rd = md + tid * (M + 1);
    int* ri = mi + tid * (M + 1);
    int* op = idx_out + (size_t)(pbase + tid) * K;
    for (int r = 0; r < K; ++r) {           // (dist, idx) lexicographic selection
        float best = 1e30f; int bj = 0x7fffffff; int bs = 0;
        for (int u = 0; u < M; ++u) {
            float dv = rd[u]; int jv = ri[u];
            if (dv < best || (dv == best && jv < bj)) { best = dv; bj = jv; bs = u; }
        }
        rd[bs] = 1e30f;
        op[r] = bj;
    }
}

// ---------------- EdgeConv: x [B*N,32] + idx + pre-transposed weights -> y [B*N,128] ----------------
template <int K>
__global__ __launch_bounds__((K == 12) ? 384 : 512, 1)
void k_edgeconv(const float* __restrict__ x, const int* __restrict__ idx,
                const float* __restrict__ WaTg, const float* __restrict__ ba,
                const float* __restrict__ WbTg, const float* __restrict__ bb,
                float* __restrict__ y) {
    constexpr int EG = (K == 12) ? 12 : 16;   // edge-groups of 4 edges
    constexpr int NT = 32 * EG;               // 384 or 512 threads
    constexpr int PI = (4 * EG) / K;          // points per iteration: 4 or 16
    constexpr int EPI = PI * K;               // edges per iteration: 48 or 64
    constexpr int PPB = 64;                   // points per block

    __shared__ __align__(16) float WaT[64 * 128];
    __shared__ __align__(16) float WbT[128 * 128];
    __shared__ __align__(16) float ba_s[128];
    __shared__ __align__(16) float bb_s[128];
    __shared__ __align__(16) float E[EPI * 72];
    __shared__ __align__(16) float H1[EPI * 132];
    __shared__ __align__(16) float P[(K == 12) ? 12 * 128 : 4];

    int tid = threadIdx.x;
    {
        const float4* sa = (const float4*)WaTg;
        const float4* sb = (const float4*)WbTg;
        float4* da = (float4*)WaT;
        float4* db = (float4*)WbT;
        for (int i = tid; i < 64 * 128 / 4; i += NT) da[i] = sa[i];
        for (int i = tid; i < 128 * 128 / 4; i += NT) db[i] = sb[i];
        if (tid < 128) { ba_s[tid] = ba[tid]; bb_s[tid] = bb[tid]; }
    }

    int b = blockIdx.x >> 7;
    int pbase = (blockIdx.x & 127) * PPB;
    const float* xb = x + ((size_t)b * NPTS) * 32;
    const int* idxb = idx + ((size_t)b * NPTS) * K;
    float* yb = y + ((size_t)b * NPTS) * 128;

    int og = tid & 31, eg = tid >> 5;

    for (int it = 0; it < PPB / PI; ++it) {
        int pt0 = pbase + it * PI;
        __syncthreads();
        for (int u = tid; u < EPI * 16; u += NT) {
            int e_i = u >> 4, c4 = u & 15;
            int p = pt0 + e_i / K;
            int kk = e_i % K;
            const float4* xip = (const float4*)(xb + (size_t)p * 32);
            float4 v;
            if (c4 < 8) {
                int j = idxb[(size_t)p * K + kk];
                float4 xj = ((const float4*)(xb + (size_t)j * 32))[c4];
                float4 xiv = xip[c4];
                v = make_float4(xj.x - xiv.x, xj.y - xiv.y, xj.z - xiv.z, xj.w - xiv.w);
            } else {
                v = xip[c4 - 8];
            }
            *(float4*)&E[e_i * 72 + 4 * c4] = v;
        }
        __syncthreads();
        float4 acc[4];
        {
            float4 bv = *(const float4*)&ba_s[4 * og];
            #pragma unroll
            for (int i = 0; i < 4; ++i) acc[i] = bv;
        }
        #pragma unroll
        for (int c = 0; c < 64; c += 4) {
            float4 w0 = *(const float4*)&WaT[(c + 0) * 128 + 4 * og];
            float4 w1 = *(const float4*)&WaT[(c + 1) * 128 + 4 * og];
            float4 w2 = *(const float4*)&WaT[(c + 2) * 128 + 4 * og];
            float4 w3 = *(const float4*)&WaT[(c + 3) * 128 + 4 * og];
            #pragma unroll
            for (int i = 0; i < 4; ++i) {
                float4 ev = *(const float4*)&E[(4 * eg + i) * 72 + c];
                acc[i].x += w0.x * ev.x + w1.x * ev.y + w2.x * ev.z + w3.x * ev.w;
                acc[i].y += w0.y * ev.x + w1.y * ev.y + w2.y * ev.z + w3.y * ev.w;
                acc[i].z += w0.z * ev.x + w1.z * ev.y + w2.z * ev.z + w3.z * ev.w;
                acc[i].w += w0.w * ev.x + w1.w * ev.y + w2.w * ev.z + w3.w * ev.w;
            }
        }
        #pragma unroll
        for (int i = 0; i < 4; ++i)
            *(float4*)&H1[(4 * eg + i) * 132 + 4 * og] = lrelu4(acc[i]);
        __syncthreads();
        float4 acc2[4];
        {
            float4 bv = *(const float4*)&bb_s[4 * og];
            #pragma unroll
            for (int i = 0; i < 4; ++i) acc2[i] = bv;
        }
        #pragma unroll
        for (int c = 0; c < 128; c += 4) {
            float4 w0 = *(const float4*)&WbT[(c + 0) * 128 + 4 * og];
            float4 w1 = *(const float4*)&WbT[(c + 1) * 128 + 4 * og];
            float4 w2 = *(const float4*)&WbT[(c + 2) * 128 + 4 * og];
            float4 w3 = *(const float4*)&WbT[(c + 3) * 128 + 4 * og];
            #pragma unroll
            for (int i = 0; i < 4; ++i) {
                float4 ev = *(const float4*)&H1[(4 * eg + i) * 132 + c];
                acc2[i].x += w0.x * ev.x + w1.x * ev.y + w2.x * ev.z + w3.x * ev.w;
                acc2[i].y += w0.y * ev.x + w1.y * ev.y + w2.y * ev.z + w3.y * ev.w;
                acc2[i].z += w0.z * ev.x + w1.z * ev.y + w2.z * ev.z + w3.z * ev.w;
                acc2[i].w += w0.w * ev.x + w1.w * ev.y + w2.w * ev.z + w3.w * ev.w;
            }
        }
        float4 m = lrelu4(acc2[0]);
        m = fmax4(m, lrelu4(acc2[1]));
        m = fmax4(m, lrelu4(acc2[2]));
        m = fmax4(m, lrelu4(acc2[3]));
        if constexpr (K == 4) {
            *(float4*)&yb[((size_t)(pt0 + eg)) * 128 + 4 * og] = m;
        } else {
            *(float4*)&P[eg * 128 + 4 * og] = m;
            __syncthreads();
            for (int u = tid; u < PI * 128; u += NT) {
                int p = u >> 7, o = u & 127;
                float v = fmaxf(fmaxf(P[(3 * p) * 128 + o], P[(3 * p + 1) * 128 + o]),
                                P[(3 * p + 2) * 128 + o]);
                yb[((size_t)(pt0 + p)) * 128 + o] = v;
            }
        }
    }
}

// ---------------- conv_mid: y [B*N,128] -> x1 [B*N,32], leaky ----------------
__global__ void k_conv_mid(const float* __restrict__ xin, const float* __restrict__ W,
                           const float* __restrict__ bias, float* __restrict__ out) {
    int gid = blockIdx.x * blockDim.x + threadIdx.x;
    const float4* row = (const float4*)(xin + (size_t)gid * 128);
    float acc[32];
    #pragma unroll
    for (int o = 0; o < 32; ++o) acc[o] = bias[o];
    #pragma unroll 2
    for (int c4 = 0; c4 < 32; ++c4) {
        float4 v = row[c4];
        #pragma unroll
        for (int o = 0; o < 32; ++o) {
            const float* w = W + o * 128 + c4 * 4;   // uniform -> s_load
            acc[o] += v.x * w[0] + v.y * w[1] + v.z * w[2] + v.w * w[3];
        }
    }
    float4* op = (float4*)(out + (size_t)gid * 32);
    #pragma unroll
    for (int o4 = 0; o4 < 8; ++o4)
        op[o4] = make_float4(lrelu(acc[o4 * 4]), lrelu(acc[o4 * 4 + 1]),
                             lrelu(acc[o4 * 4 + 2]), lrelu(acc[o4 * 4 + 3]));
}

// ---------------- decoder: y1 [B*N,128] -> out [B*N,12] ----------------
__global__ void k_decoder(const float* __restrict__ xin,
                          const float* __restrict__ W0, const float* __restrict__ b0,
                          const float* __restrict__ W1, const float* __restrict__ b1,
                          const float* __restrict__ W2, const float* __restrict__ b2,
                          float* __restrict__ out) {
    int gid = blockIdx.x * blockDim.x + threadIdx.x;
    const float4* row = (const float4*)(xin + (size_t)gid * 128);
    float h0[6];
    #pragma unroll
    for (int o = 0; o < 6; ++o) h0[o] = b0[o];
    #pragma unroll 4
    for (int c4 = 0; c4 < 32; ++c4) {
        float4 v = row[c4];
        #pragma unroll
        for (int o = 0; o < 6; ++o) {
            const float* w = W0 + o * 128 + c4 * 4;
            h0[o] += v.x * w[0] + v.y * w[1] + v.z * w[2] + v.w * w[3];
        }
    }
    #pragma unroll
    for (int o = 0; o < 6; ++o) h0[o] = lrelu(h0[o]);
    float h1[12];
    #pragma unroll
    for (int o = 0; o < 12; ++o) {
        float a = b1[o];
        #pragma unroll
        for (int j = 0; j < 6; ++j) a += W1[o * 6 + j] * h0[j];
        h1[o] = lrelu(a);
    }
    float* op = out + (size_t)gid * 12;
    #pragma unroll
    for (int o = 0; o < 12; ++o) {
        float a = b2[o];
        #pragma unroll
        for (int j = 0; j < 12; ++j) a += W2[o * 12 + j] * h1[j];
        op[o] = a;
    }
}

extern "C" void kernel_launch(void* const* d_in, const int* in_sizes, int n_in,
                              void* d_out, int out_size, void* d_ws, size_t ws_size,
                              hipStream_t stream) {
    const float* feature = (const float*)d_in[0];
    const float* Wc0 = (const float*)d_in[1];
    const float* bc0 = (const float*)d_in[2];
    const float* We0a = (const float*)d_in[3];
    const float* be0a = (const float*)d_in[4];
    const float* We0b = (const float*)d_in[5];
    const float* be0b = (const float*)d_in[6];
    const float* Wc1 = (const float*)d_in[7];
    const float* bc1 = (const float*)d_in[8];
    const float* We1a = (const float*)d_in[9];
    const float* be1a = (const float*)d_in[10];
    const float* We1b = (const float*)d_in[11];
    const float* be1b = (const float*)d_in[12];
    const float* Wd0 = (const float*)d_in[13];
    const float* bd0 = (const float*)d_in[14];
    const float* Wd1 = (const float*)d_in[15];
    const float* bd1 = (const float*)d_in[16];
    const float* Wd2 = (const float*)d_in[17];
    const float* bd2 = (const float*)d_in[18];
    float* out = (float*)d_out;

    float* f = (float*)d_ws;
    // static layout (floats), total ~22.2 MB
    float* x0   = f;                       // 524288
    float* x1   = f + 524288;              // 524288
    int*   idx0 = (int*)(f + 1048576);     // 196608
    int*   idx1 = (int*)(f + 1245184);     // 65536
    float* wT   = f + 1310720;             // 49152
    float* y0   = f + 1359872;             // 2097152
    float* y1   = f + 3457024;             // 2097152  (end 5554176)
    // candidate buffers alias the y regions (dead during kNN phases)
    float* c0d  = f + 1359872;             // 1572864 (K=12, JS=8)
    int*   c0i  = (int*)(f + 2932736);     // 1572864 (ends 4505600 < 5554176)
    float* c1d  = f + 1359872;             // 524288 (K=4, JS=8)
    int*   c1i  = (int*)(f + 1884160);     // 524288 (ends 2408448 < y0 end)
    float* WaT0 = wT;
    float* WbT0 = wT + 8192;
    float* WaT1 = wT + 24576;
    float* WbT1 = wT + 32768;

    k_transpose_w<<<192, 256, 0, stream>>>(We0a, We0b, We1a, We1b, wT);
    k_conv_in<<<64, 256, 0, stream>>>(feature, Wc0, bc0, x0);
    k_knn_cand<12, 8><<<512, 256, 0, stream>>>(x0, c0d, c0i);
    k_knn_merge<12, 8><<<256, 64, 0, stream>>>(c0d, c0i, idx0);
    k_edgeconv<12><<<256, 384, 0, stream>>>(x0, idx0, WaT0, be0a, WbT0, be0b, y0);
    k_conv_mid<<<64, 256, 0, stream>>>(y0, Wc1, bc1, x1);
    k_knn_cand<4, 8><<<512, 256, 0, stream>>>(x1, c1d, c1i);
    k_knn_merge<4, 8><<<256, 64, 0, stream>>>(c1d, c1i, idx1);
    k_edgeconv<4><<<256, 512, 0, stream>>>(x1, idx1, WaT1, be1a, WbT1, be1b, y1);
    k_decoder<<<64, 256, 0, stream>>>(y1, Wd0, bd0, Wd1, bd1, Wd2, bd2, out);
}

// Round 5
// 2085.816 us; speedup vs baseline: 3.3409x; 1.0662x over previous
//
#include <hip/hip_runtime.h>

#define NPTS 8192
#define NB 2

__device__ __forceinline__ float lrelu(float x) { return x > 0.f ? x : 0.2f * x; }
__device__ __forceinline__ float4 lrelu4(float4 a) {
    return make_float4(lrelu(a.x), lrelu(a.y), lrelu(a.z), lrelu(a.w));
}
__device__ __forceinline__ float4 fmax4(float4 a, float4 b) {
    return make_float4(fmaxf(a.x, b.x), fmaxf(a.y, b.y), fmaxf(a.z, b.z), fmaxf(a.w, b.w));
}

// ---------------- prep: transpose edge-MLP weights into ws ----------------
__global__ void k_transpose_w(const float* __restrict__ Wa0, const float* __restrict__ Wb0,
                              const float* __restrict__ Wa1, const float* __restrict__ Wb1,
                              float* __restrict__ out) {
    int t = blockIdx.x * 256 + threadIdx.x;
    if (t < 8192)       out[t] = Wa0[(t & 127) * 64 + (t >> 7)];
    else if (t < 24576) { int i = t - 8192;  out[t] = Wb0[(i & 127) * 128 + (i >> 7)]; }
    else if (t < 32768) { int i = t - 24576; out[t] = Wa1[(i & 127) * 64 + (i >> 7)]; }
    else if (t < 49152) { int i = t - 32768; out[t] = Wb1[(i & 127) * 128 + (i >> 7)]; }
}

// ---------------- conv_in: feature [B,128,N] -> x0 [B*N,32], leaky ----------------
__global__ void k_conv_in(const float* __restrict__ f, const float* __restrict__ W,
                          const float* __restrict__ bias, float* __restrict__ out) {
    int gid = blockIdx.x * blockDim.x + threadIdx.x;   // over B*N
    int b = gid >> 13, n = gid & (NPTS - 1);
    const float* fb = f + ((size_t)b << 20) + n;       // b*128*8192
    float acc[32];
    #pragma unroll
    for (int o = 0; o < 32; ++o) acc[o] = bias[o];
    #pragma unroll 4
    for (int c = 0; c < 128; ++c) {
        float xc = fb[(size_t)c * NPTS];               // coalesced across lanes
        #pragma unroll
        for (int o = 0; o < 32; ++o) acc[o] += xc * W[o * 128 + c];  // uniform -> s_load
    }
    float4* op = (float4*)(out + (size_t)gid * 32);
    #pragma unroll
    for (int o4 = 0; o4 < 8; ++o4)
        op[o4] = make_float4(lrelu(acc[o4 * 4]), lrelu(acc[o4 * 4 + 1]),
                             lrelu(acc[o4 * 4 + 2]), lrelu(acc[o4 * 4 + 3]));
}

// ---------------- kNN candidates: x [B*N,32] -> cand (top-K per j-segment) ----------------
// 1 i-point per thread; whole block scans the same j (broadcast LDS reads).
// Candidate list lives in LDS as (d, j) pairs; only scalar thr/ts in registers.
// Hot loop: 8 broadcast ds_read_b128 + 32 FMA; insert path touches LDS only.
template <int K, int JS>
__global__ __launch_bounds__(256, 2) void k_knn_cand(const float* __restrict__ x,
                                                     float* __restrict__ cand_d,
                                                     int* __restrict__ cand_i) {
    __shared__ __align__(16) float Xt[128 * 32];
    __shared__ float sqt[128];
    __shared__ __align__(8) float cl[256 * 2 * K];   // per-thread K (d,j) pairs
    constexpr int JR = NPTS / JS;           // 1024
    constexpr int BPB = (NPTS / 256) * JS;  // 256 blocks per batch

    int tid = threadIdx.x;
    int bid = blockIdx.x;
    int b = bid / BPB;
    int r0 = bid - b * BPB;
    int itile = r0 / JS;
    int jseg = r0 - itile * JS;

    const float* xb = x + ((size_t)b * NPTS) * 32;
    int pt = itile * 256 + tid;

    float4 xi[8];                            // pre-scaled by 2 (folds the -2*dot mul)
    {
        const float4* xrow = (const float4*)(xb + (size_t)pt * 32);
        #pragma unroll
        for (int u = 0; u < 8; ++u) {
            float4 v = xrow[u];
            xi[u] = make_float4(2.f * v.x, 2.f * v.y, 2.f * v.z, 2.f * v.w);
        }
    }
    float* L = cl + tid * 2 * K;
    #pragma unroll
    for (int r = 0; r < K; ++r) { L[2 * r] = 1e30f; L[2 * r + 1] = __int_as_float(0); }
    float thr = 1e30f;   // current worst (max) dist in list
    int ts = 0;          // slot holding it

    int jbase0 = jseg * JR;
    for (int t = 0; t < JR / 128; ++t) {
        int jbase = jbase0 + t * 128;
        __syncthreads();
        // contiguous staging: float4 #v of the tile (row v>>3, chunk v&7)
        const float4* gsrc = (const float4*)(xb + (size_t)jbase * 32);
        float4* dst = (float4*)Xt;
        float ss[4];
        #pragma unroll
        for (int u = 0; u < 4; ++u) {
            float4 v = gsrc[u * 256 + tid];
            dst[u * 256 + tid] = v;
            ss[u] = v.x * v.x + v.y * v.y + v.z * v.z + v.w * v.w;
        }
        #pragma unroll
        for (int u = 0; u < 4; ++u) {       // reduce the 8 chunks of each row (lanes tid&7)
            ss[u] += __shfl_xor(ss[u], 1);
            ss[u] += __shfl_xor(ss[u], 2);
            ss[u] += __shfl_xor(ss[u], 4);
        }
        if ((tid & 7) == 0) {
            #pragma unroll
            for (int u = 0; u < 4; ++u) sqt[(tid >> 3) + u * 32] = ss[u];
        }
        __syncthreads();
        #pragma unroll 2
        for (int jj = 0; jj < 128; ++jj) {
            const float4* xr = (const float4*)(Xt + jj * 32);   // broadcast (same addr all lanes)
            float da = 0.f, db = 0.f, dc = 0.f, dd4 = 0.f;      // 4 chains for ILP
            #pragma unroll
            for (int c = 0; c < 8; c += 4) {
                float4 v0 = xr[c], v1 = xr[c + 1], v2 = xr[c + 2], v3 = xr[c + 3];
                da += v0.x * xi[c].x + v0.y * xi[c].y + v0.z * xi[c].z + v0.w * xi[c].w;
                db += v1.x * xi[c + 1].x + v1.y * xi[c + 1].y + v1.z * xi[c + 1].z + v1.w * xi[c + 1].w;
                dc += v2.x * xi[c + 2].x + v2.y * xi[c + 2].y + v2.z * xi[c + 2].z + v2.w * xi[c + 2].w;
                dd4 += v3.x * xi[c + 3].x + v3.y * xi[c + 3].y + v3.z * xi[c + 3].z + v3.w * xi[c + 3].w;
            }
            float d = sqt[jj] - ((da + db) + (dc + dd4));   // rank key (sq_i const offset)
            // strict < : on distance tie the earlier (lower-index) j stays -> jax tie-break
            if (d < thr) {
                int j = jbase + jj;
                L[2 * ts] = d;                       // replace current max slot (LDS)
                L[2 * ts + 1] = __int_as_float(j);
                float m = L[0]; int mj = __float_as_int(L[1]); int ms = 0;
                #pragma unroll
                for (int r = 1; r < K; ++r) {        // rescan for new max; tie -> larger j
                    float dv = L[2 * r]; int jv = __float_as_int(L[2 * r + 1]);
                    bool c = (dv > m) || (dv == m && jv > mj);
                    m = c ? dv : m;
                    mj = c ? jv : mj;
                    ms = c ? r : ms;
                }
                thr = m; ts = ms;
            }
        }
    }
    size_t base = ((size_t)jseg * (NB * NPTS) + (size_t)b * NPTS + pt) * K;
    #pragma unroll
    for (int r = 0; r < K; ++r) {
        cand_d[base + r] = L[2 * r];
        cand_i[base + r] = __float_as_int(L[2 * r + 1]);
    }
}

// ---------------- merge JS candidate lists -> final idx [B*N, K] ----------------
template <int K, int JS>
__global__ void k_knn_merge(const float* __restrict__ cand_d, const int* __restrict__ cand_i,
                            int* __restrict__ idx_out) {
    constexpr int M = JS * K;               // 96 or 32
    __shared__ float md[64 * (M + 1)];      // stride M+1 (odd) -> 2-way max conflicts
    __shared__ int   mi[64 * (M + 1)];
    int tid = threadIdx.x;                  // 64 threads
    int pbase = blockIdx.x * 64;            // over NB*NPTS
    for (int v = tid; v < 64 * M; v += 64) {
        int s = v / (64 * K);
        int rem = v - s * 64 * K;           // p*K + r
        int p = rem / K;
        size_t g = ((size_t)s * (NB * NPTS) + pbase + p) * K + (rem - p * K);
        md[p * (M + 1) + s * K + (rem - p * K)] = cand_d[g];
        mi[p * (M + 1) + s * K + (rem - p * K)] = cand_i[g];
    }
    __syncthreads();
    float* rd = md + tid * (M + 1);
    int* ri = mi + tid * (M + 1);
    int* op = idx_out + (size_t)(pbase + tid) * K;
    for (int r = 0; r < K; ++r) {           // (dist, idx) lexicographic selection
        float best = 1e30f; int bj = 0x7fffffff; int bs = 0;
        for (int u = 0; u < M; ++u) {
            float dv = rd[u]; int jv = ri[u];
            if (dv < best || (dv == best && jv < bj)) { best = dv; bj = jv; bs = u; }
        }
        rd[bs] = 1e30f;
        op[r] = bj;
    }
}

// ---------------- EdgeConv: x [B*N,32] + idx + pre-transposed weights -> y [B*N,128] ----------------
template <int K>
__global__ __launch_bounds__((K == 12) ? 384 : 512, 1)
void k_edgeconv(const float* __restrict__ x, const int* __restrict__ idx,
                const float* __restrict__ WaTg, const float* __restrict__ ba,
                const float* __restrict__ WbTg, const float* __restrict__ bb,
                float* __restrict__ y) {
    constexpr int EG = (K == 12) ? 12 : 16;   // edge-groups of 4 edges
    constexpr int NT = 32 * EG;               // 384 or 512 threads
    constexpr int PI = (4 * EG) / K;          // points per iteration: 4 or 16
    constexpr int EPI = PI * K;               // edges per iteration: 48 or 64
    constexpr int PPB = 64;                   // points per block

    __shared__ __align__(16) float WaT[64 * 128];
    __shared__ __align__(16) float WbT[128 * 128];
    __shared__ __align__(16) float ba_s[128];
    __shared__ __align__(16) float bb_s[128];
    __shared__ __align__(16) float E[EPI * 72];
    __shared__ __align__(16) float H1[EPI * 132];
    __shared__ __align__(16) float P[(K == 12) ? 12 * 128 : 4];

    int tid = threadIdx.x;
    {
        const float4* sa = (const float4*)WaTg;
        const float4* sb = (const float4*)WbTg;
        float4* da = (float4*)WaT;
        float4* db = (float4*)WbT;
        for (int i = tid; i < 64 * 128 / 4; i += NT) da[i] = sa[i];
        for (int i = tid; i < 128 * 128 / 4; i += NT) db[i] = sb[i];
        if (tid < 128) { ba_s[tid] = ba[tid]; bb_s[tid] = bb[tid]; }
    }

    int b = blockIdx.x >> 7;
    int pbase = (blockIdx.x & 127) * PPB;
    const float* xb = x + ((size_t)b * NPTS) * 32;
    const int* idxb = idx + ((size_t)b * NPTS) * K;
    float* yb = y + ((size_t)b * NPTS) * 128;

    int og = tid & 31, eg = tid >> 5;

    for (int it = 0; it < PPB / PI; ++it) {
        int pt0 = pbase + it * PI;
        __syncthreads();
        for (int u = tid; u < EPI * 16; u += NT) {
            int e_i = u >> 4, c4 = u & 15;
            int p = pt0 + e_i / K;
            int kk = e_i % K;
            const float4* xip = (const float4*)(xb + (size_t)p * 32);
            float4 v;
            if (c4 < 8) {
                int j = idxb[(size_t)p * K + kk];
                float4 xj = ((const float4*)(xb + (size_t)j * 32))[c4];
                float4 xiv = xip[c4];
                v = make_float4(xj.x - xiv.x, xj.y - xiv.y, xj.z - xiv.z, xj.w - xiv.w);
            } else {
                v = xip[c4 - 8];
            }
            *(float4*)&E[e_i * 72 + 4 * c4] = v;
        }
        __syncthreads();
        float4 acc[4];
        {
            float4 bv = *(const float4*)&ba_s[4 * og];
            #pragma unroll
            for (int i = 0; i < 4; ++i) acc[i] = bv;
        }
        #pragma unroll
        for (int c = 0; c < 64; c += 4) {
            float4 w0 = *(const float4*)&WaT[(c + 0) * 128 + 4 * og];
            float4 w1 = *(const float4*)&WaT[(c + 1) * 128 + 4 * og];
            float4 w2 = *(const float4*)&WaT[(c + 2) * 128 + 4 * og];
            float4 w3 = *(const float4*)&WaT[(c + 3) * 128 + 4 * og];
            #pragma unroll
            for (int i = 0; i < 4; ++i) {
                float4 ev = *(const float4*)&E[(4 * eg + i) * 72 + c];
                acc[i].x += w0.x * ev.x + w1.x * ev.y + w2.x * ev.z + w3.x * ev.w;
                acc[i].y += w0.y * ev.x + w1.y * ev.y + w2.y * ev.z + w3.y * ev.w;
                acc[i].z += w0.z * ev.x + w1.z * ev.y + w2.z * ev.z + w3.z * ev.w;
                acc[i].w += w0.w * ev.x + w1.w * ev.y + w2.w * ev.z + w3.w * ev.w;
            }
        }
        #pragma unroll
        for (int i = 0; i < 4; ++i)
            *(float4*)&H1[(4 * eg + i) * 132 + 4 * og] = lrelu4(acc[i]);
        __syncthreads();
        float4 acc2[4];
        {
            float4 bv = *(const float4*)&bb_s[4 * og];
            #pragma unroll
            for (int i = 0; i < 4; ++i) acc2[i] = bv;
        }
        #pragma unroll
        for (int c = 0; c < 128; c += 4) {
            float4 w0 = *(const float4*)&WbT[(c + 0) * 128 + 4 * og];
            float4 w1 = *(const float4*)&WbT[(c + 1) * 128 + 4 * og];
            float4 w2 = *(const float4*)&WbT[(c + 2) * 128 + 4 * og];
            float4 w3 = *(const float4*)&WbT[(c + 3) * 128 + 4 * og];
            #pragma unroll
            for (int i = 0; i < 4; ++i) {
                float4 ev = *(const float4*)&H1[(4 * eg + i) * 132 + c];
                acc2[i].x += w0.x * ev.x + w1.x * ev.y + w2.x * ev.z + w3.x * ev.w;
                acc2[i].y += w0.y * ev.x + w1.y * ev.y + w2.y * ev.z + w3.y * ev.w;
                acc2[i].z += w0.z * ev.x + w1.z * ev.y + w2.z * ev.z + w3.z * ev.w;
                acc2[i].w += w0.w * ev.x + w1.w * ev.y + w2.w * ev.z + w3.w * ev.w;
            }
        }
        float4 m = lrelu4(acc2[0]);
        m = fmax4(m, lrelu4(acc2[1]));
        m = fmax4(m, lrelu4(acc2[2]));
        m = fmax4(m, lrelu4(acc2[3]));
        if constexpr (K == 4) {
            *(float4*)&yb[((size_t)(pt0 + eg)) * 128 + 4 * og] = m;
        } else {
            *(float4*)&P[eg * 128 + 4 * og] = m;
            __syncthreads();
            for (int u = tid; u < PI * 128; u += NT) {
                int p = u >> 7, o = u & 127;
                float v = fmaxf(fmaxf(P[(3 * p) * 128 + o], P[(3 * p + 1) * 128 + o]),
                                P[(3 * p + 2) * 128 + o]);
                yb[((size_t)(pt0 + p)) * 128 + o] = v;
            }
        }
    }
}

// ---------------- conv_mid: y [B*N,128] -> x1 [B*N,32], leaky ----------------
__global__ void k_conv_mid(const float* __restrict__ xin, const float* __restrict__ W,
                           const float* __restrict__ bias, float* __restrict__ out) {
    int gid = blockIdx.x * blockDim.x + threadIdx.x;
    const float4* row = (const float4*)(xin + (size_t)gid * 128);
    float acc[32];
    #pragma unroll
    for (int o = 0; o < 32; ++o) acc[o] = bias[o];
    #pragma unroll 2
    for (int c4 = 0; c4 < 32; ++c4) {
        float4 v = row[c4];
        #pragma unroll
        for (int o = 0; o < 32; ++o) {
            const float* w = W + o * 128 + c4 * 4;   // uniform -> s_load
            acc[o] += v.x * w[0] + v.y * w[1] + v.z * w[2] + v.w * w[3];
        }
    }
    float4* op = (float4*)(out + (size_t)gid * 32);
    #pragma unroll
    for (int o4 = 0; o4 < 8; ++o4)
        op[o4] = make_float4(lrelu(acc[o4 * 4]), lrelu(acc[o4 * 4 + 1]),
                             lrelu(acc[o4 * 4 + 2]), lrelu(acc[o4 * 4 + 3]));
}

// ---------------- decoder: y1 [B*N,128] -> out [B*N,12] ----------------
__global__ void k_decoder(const float* __restrict__ xin,
                          const float* __restrict__ W0, const float* __restrict__ b0,
                          const float* __restrict__ W1, const float* __restrict__ b1,
                          const float* __restrict__ W2, const float* __restrict__ b2,
                          float* __restrict__ out) {
    int gid = blockIdx.x * blockDim.x + threadIdx.x;
    const float4* row = (const float4*)(xin + (size_t)gid * 128);
    float h0[6];
    #pragma unroll
    for (int o = 0; o < 6; ++o) h0[o] = b0[o];
    #pragma unroll 4
    for (int c4 = 0; c4 < 32; ++c4) {
        float4 v = row[c4];
        #pragma unroll
        for (int o = 0; o < 6; ++o) {
            const float* w = W0 + o * 128 + c4 * 4;
            h0[o] += v.x * w[0] + v.y * w[1] + v.z * w[2] + v.w * w[3];
        }
    }
    #pragma unroll
    for (int o = 0; o < 6; ++o) h0[o] = lrelu(h0[o]);
    float h1[12];
    #pragma unroll
    for (int o = 0; o < 12; ++o) {
        float a = b1[o];
        #pragma unroll
        for (int j = 0; j < 6; ++j) a += W1[o * 6 + j] * h0[j];
        h1[o] = lrelu(a);
    }
    float* op = out + (size_t)gid * 12;
    #pragma unroll
    for (int o = 0; o < 12; ++o) {
        float a = b2[o];
        #pragma unroll
        for (int j = 0; j < 12; ++j) a += W2[o * 12 + j] * h1[j];
        op[o] = a;
    }
}

extern "C" void kernel_launch(void* const* d_in, const int* in_sizes, int n_in,
                              void* d_out, int out_size, void* d_ws, size_t ws_size,
                              hipStream_t stream) {
    const float* feature = (const float*)d_in[0];
    const float* Wc0 = (const float*)d_in[1];
    const float* bc0 = (const float*)d_in[2];
    const float* We0a = (const float*)d_in[3];
    const float* be0a = (const float*)d_in[4];
    const float* We0b = (const float*)d_in[5];
    const float* be0b = (const float*)d_in[6];
    const float* Wc1 = (const float*)d_in[7];
    const float* bc1 = (const float*)d_in[8];
    const float* We1a = (const float*)d_in[9];
    const float* be1a = (const float*)d_in[10];
    const float* We1b = (const float*)d_in[11];
    const float* be1b = (const float*)d_in[12];
    const float* Wd0 = (const float*)d_in[13];
    const float* bd0 = (const float*)d_in[14];
    const float* Wd1 = (const float*)d_in[15];
    const float* bd1 = (const float*)d_in[16];
    const float* Wd2 = (const float*)d_in[17];
    const float* bd2 = (const float*)d_in[18];
    float* out = (float*)d_out;

    float* f = (float*)d_ws;
    // static layout (floats), total ~22.2 MB
    float* x0   = f;                       // 524288
    float* x1   = f + 524288;              // 524288
    int*   idx0 = (int*)(f + 1048576);     // 196608
    int*   idx1 = (int*)(f + 1245184);     // 65536
    float* wT   = f + 1310720;             // 49152
    float* y0   = f + 1359872;             // 2097152
    float* y1   = f + 3457024;             // 2097152  (end 5554176)
    // candidate buffers alias the y regions (dead during kNN phases)
    float* c0d  = f + 1359872;             // 1572864 (K=12, JS=8)
    int*   c0i  = (int*)(f + 2932736);     // 1572864 (ends 4505600 < 5554176)
    float* c1d  = f + 1359872;             // 524288 (K=4, JS=8)
    int*   c1i  = (int*)(f + 1884160);     // 524288 (ends 2408448 < y0 end)
    float* WaT0 = wT;
    float* WbT0 = wT + 8192;
    float* WaT1 = wT + 24576;
    float* WbT1 = wT + 32768;

    k_transpose_w<<<192, 256, 0, stream>>>(We0a, We0b, We1a, We1b, wT);
    k_conv_in<<<64, 256, 0, stream>>>(feature, Wc0, bc0, x0);
    k_knn_cand<12, 8><<<512, 256, 0, stream>>>(x0, c0d, c0i);
    k_knn_merge<12, 8><<<256, 64, 0, stream>>>(c0d, c0i, idx0);
    k_edgeconv<12><<<256, 384, 0, stream>>>(x0, idx0, WaT0, be0a, WbT0, be0b, y0);
    k_conv_mid<<<64, 256, 0, stream>>>(y0, Wc1, bc1, x1);
    k_knn_cand<4, 8><<<512, 256, 0, stream>>>(x1, c1d, c1i);
    k_knn_merge<4, 8><<<256, 64, 0, stream>>>(c1d, c1i, idx1);
    k_edgeconv<4><<<256, 512, 0, stream>>>(x1, idx1, WaT1, be1a, WbT1, be1b, y1);
    k_decoder<<<64, 256, 0, stream>>>(y1, Wd0, bd0, Wd1, bd1, Wd2, bd2, out);
}

// Round 6
// 1600.300 us; speedup vs baseline: 4.3545x; 1.3034x over previous
//
#include <hip/hip_runtime.h>

#define NPTS 8192
#define NB 2

__device__ __forceinline__ float lrelu(float x) { return x > 0.f ? x : 0.2f * x; }
__device__ __forceinline__ float4 lrelu4(float4 a) {
    return make_float4(lrelu(a.x), lrelu(a.y), lrelu(a.z), lrelu(a.w));
}
__device__ __forceinline__ float4 fmax4(float4 a, float4 b) {
    return make_float4(fmaxf(a.x, b.x), fmaxf(a.y, b.y), fmaxf(a.z, b.z), fmaxf(a.w, b.w));
}

// ---------------- prep: transpose edge-MLP weights into ws ----------------
__global__ void k_transpose_w(const float* __restrict__ Wa0, const float* __restrict__ Wb0,
                              const float* __restrict__ Wa1, const float* __restrict__ Wb1,
                              float* __restrict__ out) {
    int t = blockIdx.x * 256 + threadIdx.x;
    if (t < 8192)       out[t] = Wa0[(t & 127) * 64 + (t >> 7)];
    else if (t < 24576) { int i = t - 8192;  out[t] = Wb0[(i & 127) * 128 + (i >> 7)]; }
    else if (t < 32768) { int i = t - 24576; out[t] = Wa1[(i & 127) * 64 + (i >> 7)]; }
    else if (t < 49152) { int i = t - 32768; out[t] = Wb1[(i & 127) * 128 + (i >> 7)]; }
}

// ---------------- conv_in: feature [B,128,N] -> x0 [B*N,32], leaky ----------------
__global__ void k_conv_in(const float* __restrict__ f, const float* __restrict__ W,
                          const float* __restrict__ bias, float* __restrict__ out) {
    int gid = blockIdx.x * blockDim.x + threadIdx.x;   // over B*N
    int b = gid >> 13, n = gid & (NPTS - 1);
    const float* fb = f + ((size_t)b << 20) + n;       // b*128*8192
    float acc[32];
    #pragma unroll
    for (int o = 0; o < 32; ++o) acc[o] = bias[o];
    #pragma unroll 4
    for (int c = 0; c < 128; ++c) {
        float xc = fb[(size_t)c * NPTS];               // coalesced across lanes
        #pragma unroll
        for (int o = 0; o < 32; ++o) acc[o] += xc * W[o * 128 + c];  // uniform -> s_load
    }
    float4* op = (float4*)(out + (size_t)gid * 32);
    #pragma unroll
    for (int o4 = 0; o4 < 8; ++o4)
        op[o4] = make_float4(lrelu(acc[o4 * 4]), lrelu(acc[o4 * 4 + 1]),
                             lrelu(acc[o4 * 4 + 2]), lrelu(acc[o4 * 4 + 3]));
}

// ---------------- kNN candidates: x [B*N,32] -> cand (top-K per j-segment) ----------------
// 1 i-point per thread; whole block scans the same j (broadcast LDS reads).
// Sorted top-K lives in REGISTERS; hot loop only appends (d,j) to a transposed
// LDS buffer; wave-collective flush drains buffer via static insertion chain.
template <int K, int JS, int C>
__global__ __launch_bounds__(256, 2) void k_knn_cand(const float* __restrict__ x,
                                                     float* __restrict__ cand_d,
                                                     int* __restrict__ cand_i) {
    __shared__ __align__(16) float Xt[128 * 32];
    __shared__ float sqt[128];
    __shared__ float bufd[C * 256];          // transposed: slot*256 + tid (conflict-free)
    __shared__ int   bufj[C * 256];
    constexpr int JR = NPTS / JS;            // 1024
    constexpr int BPB = (NPTS / 256) * JS;   // 256 blocks per batch

    int tid = threadIdx.x;
    int bid = blockIdx.x;
    int b = bid / BPB;
    int r0 = bid - b * BPB;
    int itile = r0 / JS;
    int jseg = r0 - itile * JS;

    const float* xb = x + ((size_t)b * NPTS) * 32;
    int pt = itile * 256 + tid;

    float4 xi[8];                            // pre-scaled by 2 (folds the -2*dot mul)
    {
        const float4* xrow = (const float4*)(xb + (size_t)pt * 32);
        #pragma unroll
        for (int u = 0; u < 8; ++u) {
            float4 v = xrow[u];
            xi[u] = make_float4(2.f * v.x, 2.f * v.y, 2.f * v.z, 2.f * v.w);
        }
    }
    float bd[K]; int bi[K];                  // sorted ascending, registers
    #pragma unroll
    for (int r = 0; r < K; ++r) { bd[r] = 1e30f; bi[r] = 0; }
    float thr = 1e30f;
    int cnt = 0;

    // drain buffer into sorted register list (R3-proven insertion semantics)
    auto flush = [&]() {
        #pragma unroll
        for (int u = 0; u < C; ++u) {
            float dv = bufd[u * 256 + tid];
            int jv = bufj[u * 256 + tid];
            bool valid = u < cnt;
            float dd = valid ? dv : 1e30f;   // 1e30 never inserts (strict <)
            int ji = jv;
            #pragma unroll
            for (int r = 0; r < K; ++r) {
                bool c = dd < bd[r];
                float tf = bd[r]; int ti = bi[r];
                bd[r] = c ? dd : bd[r]; bi[r] = c ? ji : bi[r];
                dd = c ? tf : dd;       ji = c ? ti : ji;
            }
        }
        cnt = 0; thr = bd[K - 1];
    };

    int jbase0 = jseg * JR;
    for (int t = 0; t < JR / 128; ++t) {
        int jbase = jbase0 + t * 128;
        __syncthreads();
        // contiguous staging: float4 #v of the tile (row v>>3, chunk v&7)
        const float4* gsrc = (const float4*)(xb + (size_t)jbase * 32);
        float4* dst = (float4*)Xt;
        float ss[4];
        #pragma unroll
        for (int u = 0; u < 4; ++u) {
            float4 v = gsrc[u * 256 + tid];
            dst[u * 256 + tid] = v;
            ss[u] = v.x * v.x + v.y * v.y + v.z * v.z + v.w * v.w;
        }
        #pragma unroll
        for (int u = 0; u < 4; ++u) {       // reduce the 8 chunks of each row (lanes tid&7)
            ss[u] += __shfl_xor(ss[u], 1);
            ss[u] += __shfl_xor(ss[u], 2);
            ss[u] += __shfl_xor(ss[u], 4);
        }
        if ((tid & 7) == 0) {
            #pragma unroll
            for (int u = 0; u < 4; ++u) sqt[(tid >> 3) + u * 32] = ss[u];
        }
        __syncthreads();
        #pragma unroll 1
        for (int jj = 0; jj < 128; ++jj) {
            const float4* xr = (const float4*)(Xt + jj * 32);   // broadcast (same addr all lanes)
            float da = 0.f, db = 0.f, dc = 0.f, dd4 = 0.f;      // 4 chains for ILP
            #pragma unroll
            for (int c = 0; c < 8; c += 4) {
                float4 v0 = xr[c], v1 = xr[c + 1], v2 = xr[c + 2], v3 = xr[c + 3];
                da += v0.x * xi[c].x + v0.y * xi[c].y + v0.z * xi[c].z + v0.w * xi[c].w;
                db += v1.x * xi[c + 1].x + v1.y * xi[c + 1].y + v1.z * xi[c + 1].z + v1.w * xi[c + 1].w;
                dc += v2.x * xi[c + 2].x + v2.y * xi[c + 2].y + v2.z * xi[c + 2].z + v2.w * xi[c + 2].w;
                dd4 += v3.x * xi[c + 3].x + v3.y * xi[c + 3].y + v3.z * xi[c + 3].z + v3.w * xi[c + 3].w;
            }
            float d = sqt[jj] - ((da + db) + (dc + dd4));   // rank key (sq_i const offset)
            // strict < : on tie the earlier (lower-index) j stays -> jax tie-break
            if (d < thr) {                   // tiny divergent append, conflict-free
                bufd[cnt * 256 + tid] = d;
                bufj[cnt * 256 + tid] = jbase + jj;
                cnt++;
            }
            if (__any(cnt >= C)) flush();    // wave-collective, infrequent
        }
    }
    flush();
    size_t base = ((size_t)jseg * (NB * NPTS) + (size_t)b * NPTS + pt) * K;
    #pragma unroll
    for (int r = 0; r < K; ++r) { cand_d[base + r] = bd[r]; cand_i[base + r] = bi[r]; }
}

// ---------------- merge JS candidate lists -> final idx [B*N, K] ----------------
template <int K, int JS>
__global__ void k_knn_merge(const float* __restrict__ cand_d, const int* __restrict__ cand_i,
                            int* __restrict__ idx_out) {
    constexpr int M = JS * K;               // 96 or 32
    __shared__ float md[64 * (M + 1)];      // stride M+1 (odd) -> 2-way max conflicts
    __shared__ int   mi[64 * (M + 1)];
    int tid = threadIdx.x;                  // 64 threads
    int pbase = blockIdx.x * 64;            // over NB*NPTS
    for (int v = tid; v < 64 * M; v += 64) {
        int s = v / (64 * K);
        int rem = v - s * 64 * K;           // p*K + r
        int p = rem / K;
        size_t g = ((size_t)s * (NB * NPTS) + pbase + p) * K + (rem - p * K);
        md[p * (M + 1) + s * K + (rem - p * K)] = cand_d[g];
        mi[p * (M + 1) + s * K + (rem - p * K)] = cand_i[g];
    }
    __syncthreads();
    float* rd = md + tid * (M + 1);
    int* ri = mi + tid * (M + 1);
    int* op = idx_out + (size_t)(pbase + tid) * K;
    for (int r = 0; r < K; ++r) {           // (dist, idx) lexicographic selection
        float best = 1e30f; int bj = 0x7fffffff; int bs = 0;
        for (int u = 0; u < M; ++u) {
            float dv = rd[u]; int jv = ri[u];
            if (dv < best || (dv == best && jv < bj)) { best = dv; bj = jv; bs = u; }
        }
        rd[bs] = 1e30f;
        op[r] = bj;
    }
}

// ---------------- EdgeConv: x [B*N,32] + idx + pre-transposed weights -> y [B*N,128] ----------------
template <int K>
__global__ __launch_bounds__((K == 12) ? 384 : 512, 1)
void k_edgeconv(const float* __restrict__ x, const int* __restrict__ idx,
                const float* __restrict__ WaTg, const float* __restrict__ ba,
                const float* __restrict__ WbTg, const float* __restrict__ bb,
                float* __restrict__ y) {
    constexpr int EG = (K == 12) ? 12 : 16;   // edge-groups of 4 edges
    constexpr int NT = 32 * EG;               // 384 or 512 threads
    constexpr int PI = (4 * EG) / K;          // points per iteration: 4 or 16
    constexpr int EPI = PI * K;               // edges per iteration: 48 or 64
    constexpr int PPB = 64;                   // points per block

    __shared__ __align__(16) float WaT[64 * 128];
    __shared__ __align__(16) float WbT[128 * 128];
    __shared__ __align__(16) float ba_s[128];
    __shared__ __align__(16) float bb_s[128];
    __shared__ __align__(16) float E[EPI * 72];
    __shared__ __align__(16) float H1[EPI * 132];
    __shared__ __align__(16) float P[(K == 12) ? 12 * 128 : 4];

    int tid = threadIdx.x;
    {
        const float4* sa = (const float4*)WaTg;
        const float4* sb = (const float4*)WbTg;
        float4* da = (float4*)WaT;
        float4* db = (float4*)WbT;
        for (int i = tid; i < 64 * 128 / 4; i += NT) da[i] = sa[i];
        for (int i = tid; i < 128 * 128 / 4; i += NT) db[i] = sb[i];
        if (tid < 128) { ba_s[tid] = ba[tid]; bb_s[tid] = bb[tid]; }
    }

    int b = blockIdx.x >> 7;
    int pbase = (blockIdx.x & 127) * PPB;
    const float* xb = x + ((size_t)b * NPTS) * 32;
    const int* idxb = idx + ((size_t)b * NPTS) * K;
    float* yb = y + ((size_t)b * NPTS) * 128;

    int og = tid & 31, eg = tid >> 5;

    for (int it = 0; it < PPB / PI; ++it) {
        int pt0 = pbase + it * PI;
        __syncthreads();
        for (int u = tid; u < EPI * 16; u += NT) {
            int e_i = u >> 4, c4 = u & 15;
            int p = pt0 + e_i / K;
            int kk = e_i % K;
            const float4* xip = (const float4*)(xb + (size_t)p * 32);
            float4 v;
            if (c4 < 8) {
                int j = idxb[(size_t)p * K + kk];
                float4 xj = ((const float4*)(xb + (size_t)j * 32))[c4];
                float4 xiv = xip[c4];
                v = make_float4(xj.x - xiv.x, xj.y - xiv.y, xj.z - xiv.z, xj.w - xiv.w);
            } else {
                v = xip[c4 - 8];
            }
            *(float4*)&E[e_i * 72 + 4 * c4] = v;
        }
        __syncthreads();
        float4 acc[4];
        {
            float4 bv = *(const float4*)&ba_s[4 * og];
            #pragma unroll
            for (int i = 0; i < 4; ++i) acc[i] = bv;
        }
        #pragma unroll
        for (int c = 0; c < 64; c += 4) {
            float4 w0 = *(const float4*)&WaT[(c + 0) * 128 + 4 * og];
            float4 w1 = *(const float4*)&WaT[(c + 1) * 128 + 4 * og];
            float4 w2 = *(const float4*)&WaT[(c + 2) * 128 + 4 * og];
            float4 w3 = *(const float4*)&WaT[(c + 3) * 128 + 4 * og];
            #pragma unroll
            for (int i = 0; i < 4; ++i) {
                float4 ev = *(const float4*)&E[(4 * eg + i) * 72 + c];
                acc[i].x += w0.x * ev.x + w1.x * ev.y + w2.x * ev.z + w3.x * ev.w;
                acc[i].y += w0.y * ev.x + w1.y * ev.y + w2.y * ev.z + w3.y * ev.w;
                acc[i].z += w0.z * ev.x + w1.z * ev.y + w2.z * ev.z + w3.z * ev.w;
                acc[i].w += w0.w * ev.x + w1.w * ev.y + w2.w * ev.z + w3.w * ev.w;
            }
        }
        #pragma unroll
        for (int i = 0; i < 4; ++i)
            *(float4*)&H1[(4 * eg + i) * 132 + 4 * og] = lrelu4(acc[i]);
        __syncthreads();
        float4 acc2[4];
        {
            float4 bv = *(const float4*)&bb_s[4 * og];
            #pragma unroll
            for (int i = 0; i < 4; ++i) acc2[i] = bv;
        }
        #pragma unroll
        for (int c = 0; c < 128; c += 4) {
            float4 w0 = *(const float4*)&WbT[(c + 0) * 128 + 4 * og];
            float4 w1 = *(const float4*)&WbT[(c + 1) * 128 + 4 * og];
            float4 w2 = *(const float4*)&WbT[(c + 2) * 128 + 4 * og];
            float4 w3 = *(const float4*)&WbT[(c + 3) * 128 + 4 * og];
            #pragma unroll
            for (int i = 0; i < 4; ++i) {
                float4 ev = *(const float4*)&H1[(4 * eg + i) * 132 + c];
                acc2[i].x += w0.x * ev.x + w1.x * ev.y + w2.x * ev.z + w3.x * ev.w;
                acc2[i].y += w0.y * ev.x + w1.y * ev.y + w2.y * ev.z + w3.y * ev.w;
                acc2[i].z += w0.z * ev.x + w1.z * ev.y + w2.z * ev.z + w3.z * ev.w;
                acc2[i].w += w0.w * ev.x + w1.w * ev.y + w2.w * ev.z + w3.w * ev.w;
            }
        }
        float4 m = lrelu4(acc2[0]);
        m = fmax4(m, lrelu4(acc2[1]));
        m = fmax4(m, lrelu4(acc2[2]));
        m = fmax4(m, lrelu4(acc2[3]));
        if constexpr (K == 4) {
            *(float4*)&yb[((size_t)(pt0 + eg)) * 128 + 4 * og] = m;
        } else {
            *(float4*)&P[eg * 128 + 4 * og] = m;
            __syncthreads();
            for (int u = tid; u < PI * 128; u += NT) {
                int p = u >> 7, o = u & 127;
                float v = fmaxf(fmaxf(P[(3 * p) * 128 + o], P[(3 * p + 1) * 128 + o]),
                                P[(3 * p + 2) * 128 + o]);
                yb[((size_t)(pt0 + p)) * 128 + o] = v;
            }
        }
    }
}

// ---------------- conv_mid: y [B*N,128] -> x1 [B*N,32], leaky ----------------
__global__ void k_conv_mid(const float* __restrict__ xin, const float* __restrict__ W,
                           const float* __restrict__ bias, float* __restrict__ out) {
    int gid = blockIdx.x * blockDim.x + threadIdx.x;
    const float4* row = (const float4*)(xin + (size_t)gid * 128);
    float acc[32];
    #pragma unroll
    for (int o = 0; o < 32; ++o) acc[o] = bias[o];
    #pragma unroll 2
    for (int c4 = 0; c4 < 32; ++c4) {
        float4 v = row[c4];
        #pragma unroll
        for (int o = 0; o < 32; ++o) {
            const float* w = W + o * 128 + c4 * 4;   // uniform -> s_load
            acc[o] += v.x * w[0] + v.y * w[1] + v.z * w[2] + v.w * w[3];
        }
    }
    float4* op = (float4*)(out + (size_t)gid * 32);
    #pragma unroll
    for (int o4 = 0; o4 < 8; ++o4)
        op[o4] = make_float4(lrelu(acc[o4 * 4]), lrelu(acc[o4 * 4 + 1]),
                             lrelu(acc[o4 * 4 + 2]), lrelu(acc[o4 * 4 + 3]));
}

// ---------------- decoder: y1 [B*N,128] -> out [B*N,12] ----------------
__global__ void k_decoder(const float* __restrict__ xin,
                          const float* __restrict__ W0, const float* __restrict__ b0,
                          const float* __restrict__ W1, const float* __restrict__ b1,
                          const float* __restrict__ W2, const float* __restrict__ b2,
                          float* __restrict__ out) {
    int gid = blockIdx.x * blockDim.x + threadIdx.x;
    const float4* row = (const float4*)(xin + (size_t)gid * 128);
    float h0[6];
    #pragma unroll
    for (int o = 0; o < 6; ++o) h0[o] = b0[o];
    #pragma unroll 4
    for (int c4 = 0; c4 < 32; ++c4) {
        float4 v = row[c4];
        #pragma unroll
        for (int o = 0; o < 6; ++o) {
            const float* w = W0 + o * 128 + c4 * 4;
            h0[o] += v.x * w[0] + v.y * w[1] + v.z * w[2] + v.w * w[3];
        }
    }
    #pragma unroll
    for (int o = 0; o < 6; ++o) h0[o] = lrelu(h0[o]);
    float h1[12];
    #pragma unroll
    for (int o = 0; o < 12; ++o) {
        float a = b1[o];
        #pragma unroll
        for (int j = 0; j < 6; ++j) a += W1[o * 6 + j] * h0[j];
        h1[o] = lrelu(a);
    }
    float* op = out + (size_t)gid * 12;
    #pragma unroll
    for (int o = 0; o < 12; ++o) {
        float a = b2[o];
        #pragma unroll
        for (int j = 0; j < 12; ++j) a += W2[o * 12 + j] * h1[j];
        op[o] = a;
    }
}

extern "C" void kernel_launch(void* const* d_in, const int* in_sizes, int n_in,
                              void* d_out, int out_size, void* d_ws, size_t ws_size,
                              hipStream_t stream) {
    const float* feature = (const float*)d_in[0];
    const float* Wc0 = (const float*)d_in[1];
    const float* bc0 = (const float*)d_in[2];
    const float* We0a = (const float*)d_in[3];
    const float* be0a = (const float*)d_in[4];
    const float* We0b = (const float*)d_in[5];
    const float* be0b = (const float*)d_in[6];
    const float* Wc1 = (const float*)d_in[7];
    const float* bc1 = (const float*)d_in[8];
    const float* We1a = (const float*)d_in[9];
    const float* be1a = (const float*)d_in[10];
    const float* We1b = (const float*)d_in[11];
    const float* be1b = (const float*)d_in[12];
    const float* Wd0 = (const float*)d_in[13];
    const float* bd0 = (const float*)d_in[14];
    const float* Wd1 = (const float*)d_in[15];
    const float* bd1 = (const float*)d_in[16];
    const float* Wd2 = (const float*)d_in[17];
    const float* bd2 = (const float*)d_in[18];
    float* out = (float*)d_out;

    float* f = (float*)d_ws;
    // static layout (floats), total ~22.2 MB
    float* x0   = f;                       // 524288
    float* x1   = f + 524288;              // 524288
    int*   idx0 = (int*)(f + 1048576);     // 196608
    int*   idx1 = (int*)(f + 1245184);     // 65536
    float* wT   = f + 1310720;             // 49152
    float* y0   = f + 1359872;             // 2097152
    float* y1   = f + 3457024;             // 2097152  (end 5554176)
    // candidate buffers alias the y regions (dead during kNN phases)
    float* c0d  = f + 1359872;             // 1572864 (K=12, JS=8)
    int*   c0i  = (int*)(f + 2932736);     // 1572864 (ends 4505600 < 5554176)
    float* c1d  = f + 1359872;             // 524288 (K=4, JS=8)
    int*   c1i  = (int*)(f + 1884160);     // 524288 (ends 2408448 < y0 end)
    float* WaT0 = wT;
    float* WbT0 = wT + 8192;
    float* WaT1 = wT + 24576;
    float* WbT1 = wT + 32768;

    k_transpose_w<<<192, 256, 0, stream>>>(We0a, We0b, We1a, We1b, wT);
    k_conv_in<<<64, 256, 0, stream>>>(feature, Wc0, bc0, x0);
    k_knn_cand<12, 8, 12><<<512, 256, 0, stream>>>(x0, c0d, c0i);
    k_knn_merge<12, 8><<<256, 64, 0, stream>>>(c0d, c0i, idx0);
    k_edgeconv<12><<<256, 384, 0, stream>>>(x0, idx0, WaT0, be0a, WbT0, be0b, y0);
    k_conv_mid<<<64, 256, 0, stream>>>(y0, Wc1, bc1, x1);
    k_knn_cand<4, 8, 8><<<512, 256, 0, stream>>>(x1, c1d, c1i);
    k_knn_merge<4, 8><<<256, 64, 0, stream>>>(c1d, c1i, idx1);
    k_edgeconv<4><<<256, 512, 0, stream>>>(x1, idx1, WaT1, be1a, WbT1, be1b, y1);
    k_decoder<<<64, 256, 0, stream>>>(y1, Wd0, bd0, Wd1, bd1, Wd2, bd2, out);
}